// Round 1
// baseline (715.834 us; speedup 1.0000x reference)
//
#include <hip/hip_runtime.h>
#include <hip/hip_bf16.h>
#include <stdint.h>

typedef unsigned short u16;
typedef short bf16x8 __attribute__((ext_vector_type(8)));
typedef float f32x4 __attribute__((ext_vector_type(4)));

#define GLOAD16(gp, lp) __builtin_amdgcn_global_load_lds( \
    (const __attribute__((address_space(1))) uint32_t*)(gp), \
    (__attribute__((address_space(3))) uint32_t*)(lp), 16, 0, 0)

__device__ __forceinline__ u16 f2bf(float f) {
  union { float f; uint32_t u; } x; x.f = f;
  return (u16)((x.u + 0x7FFFu + ((x.u >> 16) & 1u)) >> 16);
}

// ---------------- cast x (f32 -> bf16), vectorized ----------------
__global__ void cast_x_kernel(const float* __restrict__ in, u16* __restrict__ out, long n) {
  long stride = (long)gridDim.x * blockDim.x * 8;
  for (long i = ((long)blockIdx.x * blockDim.x + threadIdx.x) * 8; i < n; i += stride) {
    float4 a = *(const float4*)&in[i];
    float4 b = *(const float4*)&in[i + 4];
    u16 o[8];
    o[0] = f2bf(a.x); o[1] = f2bf(a.y); o[2] = f2bf(a.z); o[3] = f2bf(a.w);
    o[4] = f2bf(b.x); o[5] = f2bf(b.y); o[6] = f2bf(b.z); o[7] = f2bf(b.w);
    *(uint4*)&out[i] = *(const uint4*)o;
  }
}

// ------------- cast + transpose the 4 weights: wt[n][k] = w[k][n] -------------
__global__ void cast_w_kernel(const float* __restrict__ w0, const float* __restrict__ w1,
                              const float* __restrict__ w2, const float* __restrict__ w3,
                              u16* __restrict__ out) {
  const float* w = blockIdx.z == 0 ? w0 : blockIdx.z == 1 ? w1 : blockIdx.z == 2 ? w2 : w3;
  u16* o = out + (size_t)blockIdx.z * 1024 * 1024;
  __shared__ float tile[64][65];
  const int t = threadIdx.x;
  const int lr = t >> 2, lc = (t & 3) * 16;
  const int r0 = blockIdx.y * 64, c0 = blockIdx.x * 64;
  const float* src = w + (size_t)(r0 + lr) * 1024 + c0 + lc;
#pragma unroll
  for (int j = 0; j < 4; ++j) {
    float4 v = *(const float4*)&src[j * 4];
    tile[lr][lc + j * 4 + 0] = v.x;
    tile[lr][lc + j * 4 + 1] = v.y;
    tile[lr][lc + j * 4 + 2] = v.z;
    tile[lr][lc + j * 4 + 3] = v.w;
  }
  __syncthreads();
  u16 tmp[16];
#pragma unroll
  for (int j = 0; j < 16; ++j) tmp[j] = f2bf(tile[lc + j][lr]);
  u16* dst = o + (size_t)(c0 + lr) * 1024 + r0 + lc;
  *(uint4*)&dst[0] = *(const uint4*)&tmp[0];
  *(uint4*)&dst[8] = *(const uint4*)&tmp[8];
}

// ---------------- generic NT GEMM: C[M,N] = A[M,K] * B[N,K]^T ----------------
// 128x128 tile, BK=64, 256 threads (4 waves, 2x2), mfma_f32_16x16x32_bf16,
// global_load_lds width-16 staging, XOR-swizzled LDS (pre-swizzled source).
template <bool F32OUT>
__global__ __launch_bounds__(256) void gemm_bt(const u16* __restrict__ A,
                                               const u16* __restrict__ B,
                                               void* __restrict__ C,
                                               int lda, int ldb, int ldc, int K) {
  __shared__ u16 lds[2 * 8192];  // A tile [128][64] @0, B tile [128][64] @8192 (u16 units)
  const int t = threadIdx.x;
  const int l = t & 63;
  const int w = t >> 6;
  const int wr = w >> 1, wc = w & 1;
  const int lr16 = l & 15, hi = l >> 4;
  const int mBase = blockIdx.y * 128;
  const int nBase = blockIdx.x * 128;

  f32x4 acc[4][4];
#pragma unroll
  for (int m = 0; m < 4; ++m)
#pragma unroll
    for (int n = 0; n < 4; ++n) acc[m][n] = (f32x4){0.f, 0.f, 0.f, 0.f};

  for (int kt = 0; kt < K; kt += 64) {
    __syncthreads();  // all waves done reading LDS from previous tile
    // stage A tile: 128 rows x 64 k (16KB) = 4 x (256 lanes x 16B)
#pragma unroll
    for (int i = 0; i < 4; ++i) {
      int s = i * 256 + t;              // 16B slot index, linear in LDS
      int row = s >> 3, cp = s & 7;     // physical chunk
      int clog = cp ^ (row & 7);        // pre-swizzled source chunk
      const u16* g = A + (size_t)(mBase + row) * lda + kt + clog * 8;
      GLOAD16(g, &lds[s * 8]);
    }
#pragma unroll
    for (int i = 0; i < 4; ++i) {
      int s = i * 256 + t;
      int row = s >> 3, cp = s & 7;
      int clog = cp ^ (row & 7);
      const u16* g = B + (size_t)(nBase + row) * ldb + kt + clog * 8;
      GLOAD16(g, &lds[8192 + s * 8]);
    }
    asm volatile("s_waitcnt vmcnt(0)" ::: "memory");
    __syncthreads();
#pragma unroll
    for (int ks = 0; ks < 2; ++ks) {
      bf16x8 af[4], bfr[4];
#pragma unroll
      for (int m = 0; m < 4; ++m) {
        int row = wr * 64 + m * 16 + lr16;
        int p = (ks * 4 + hi) ^ (row & 7);
        af[m] = *(const bf16x8*)&lds[row * 64 + p * 8];
      }
#pragma unroll
      for (int n = 0; n < 4; ++n) {
        int row = wc * 64 + n * 16 + lr16;
        int p = (ks * 4 + hi) ^ (row & 7);
        bfr[n] = *(const bf16x8*)&lds[8192 + row * 64 + p * 8];
      }
#pragma unroll
      for (int m = 0; m < 4; ++m)
#pragma unroll
        for (int n = 0; n < 4; ++n)
          acc[m][n] = __builtin_amdgcn_mfma_f32_16x16x32_bf16(af[m], bfr[n], acc[m][n], 0, 0, 0);
    }
  }

  // epilogue: C/D layout col=lane&15, row=(lane>>4)*4+reg (m89/m91 verified)
#pragma unroll
  for (int m = 0; m < 4; ++m) {
    int row0 = mBase + wr * 64 + m * 16 + hi * 4;
#pragma unroll
    for (int n = 0; n < 4; ++n) {
      int col = nBase + wc * 64 + n * 16 + lr16;
      f32x4 v = acc[m][n];
      if (F32OUT) {
        float* Cf = (float*)C;
#pragma unroll
        for (int r = 0; r < 4; ++r) Cf[(size_t)(row0 + r) * ldc + col] = v[r];
      } else {
        u16* Cb = (u16*)C;
#pragma unroll
        for (int r = 0; r < 4; ++r) Cb[(size_t)(row0 + r) * ldc + col] = f2bf(v[r]);
      }
    }
  }
}

// ---------------- host-side orchestration ----------------
extern "C" void kernel_launch(void* const* d_in, const int* in_sizes, int n_in,
                              void* d_out, int out_size, void* d_ws, size_t ws_size,
                              hipStream_t stream) {
  const float* x  = (const float*)d_in[0];
  const float* wq = (const float*)d_in[1];
  const float* wk = (const float*)d_in[2];
  const float* wv = (const float*)d_in[3];
  const float* wo = (const float*)d_in[4];
  float* out = (float*)d_out;

  // workspace layout (u16 elements):
  // xb (16M, reused as attn) | Q (16M) | K (16M) | Vt (16M) | scores (16M, per-batch) | Wt (4M)
  u16* ws = (u16*)d_ws;
  u16* xb = ws;                     // [16384][1024] bf16; later attn [16384][1024]
  u16* Qm = ws + 16777216;          // [16384][1024]
  u16* Km = ws + 33554432;          // [16384][1024]
  u16* Vt = ws + 50331648;          // [1024][16384]  (V transposed, all batches as columns)
  u16* Sc = ws + 67108864;          // [4096][4096]   (one batch of scores, reused)
  u16* Wt = ws + 83886080;          // 4 x [1024][1024] transposed weights
  const size_t WSTRIDE = 1024 * 1024;
  const size_t SLICE = (size_t)4096 * 1024;  // per-batch token slice

  // 1) casts
  cast_x_kernel<<<2048, 256, 0, stream>>>(x, xb, (long)4 * 4096 * 1024);
  cast_w_kernel<<<dim3(16, 16, 4), 256, 0, stream>>>(wq, wk, wv, wo, Wt);

  // 2) Q = xb @ wq   (NT vs transposed weight): M=16384 N=1024 K=1024
  gemm_bt<false><<<dim3(8, 128), 256, 0, stream>>>(xb, Wt + 0 * WSTRIDE, Qm, 1024, 1024, 1024, 1024);
  // 3) K = xb @ wk
  gemm_bt<false><<<dim3(8, 128), 256, 0, stream>>>(xb, Wt + 1 * WSTRIDE, Km, 1024, 1024, 1024, 1024);
  // 4) Vt[d][token] = sum_k wv[k][d] x[token][k]: M=1024 N=16384 K=1024
  gemm_bt<false><<<dim3(128, 8), 256, 0, stream>>>(Wt + 2 * WSTRIDE, xb, Vt, 1024, 1024, 16384, 1024);

  // 5) per batch: scores = Q_b @ K_b^T (M=N=4096 K=1024), attn_b = scores @ Vt_b^T (M=4096 N=1024 K=4096)
  for (int b = 0; b < 4; ++b) {
    gemm_bt<false><<<dim3(32, 32), 256, 0, stream>>>(Qm + b * SLICE, Km + b * SLICE, Sc,
                                                     1024, 1024, 4096, 1024);
    // attn written into xb (xb no longer needed)
    gemm_bt<false><<<dim3(8, 32), 256, 0, stream>>>(Sc, Vt + b * 4096, xb + b * SLICE,
                                                    4096, 16384, 1024, 4096);
  }

  // 6) out = attn @ wo : M=16384 N=1024 K=1024, f32 output
  gemm_bt<true><<<dim3(8, 128), 256, 0, stream>>>(xb, Wt + 3 * WSTRIDE, out, 1024, 1024, 1024, 1024);
}

// Round 2
// 242.096 us; speedup vs baseline: 2.9568x; 2.9568x over previous
//
#include <hip/hip_runtime.h>
#include <hip/hip_bf16.h>
#include <stdint.h>

typedef unsigned short u16;
typedef short bf16x8 __attribute__((ext_vector_type(8)));
typedef float f32x4 __attribute__((ext_vector_type(4)));

#define GLOAD16(gp, lp) __builtin_amdgcn_global_load_lds( \
    (const __attribute__((address_space(1))) uint32_t*)(gp), \
    (__attribute__((address_space(3))) uint32_t*)(lp), 16, 0, 0)

__device__ __forceinline__ u16 f2bf(float f) {
  union { float f; uint32_t u; } x; x.f = f;
  return (u16)((x.u + 0x7FFFu + ((x.u >> 16) & 1u)) >> 16);
}

// ------- cast x: xb[t][d] bf16 (plain) AND xT[d][t] bf16 (transposed) -------
// x is [16384][1024] f32 (batch-major tokens). 64x64 tiles.
__global__ __launch_bounds__(256) void cast_x_tr(const float* __restrict__ x,
                                                 u16* __restrict__ xb,
                                                 u16* __restrict__ xT) {
  __shared__ float tile[64][65];
  const int t = threadIdx.x;
  const int lr = t >> 2, lc = (t & 3) * 16;
  const int d0 = blockIdx.x * 64;   // d tile (16)
  const int t0 = blockIdx.y * 64;   // token tile (256)
  const float* src = x + (size_t)(t0 + lr) * 1024 + d0 + lc;
  u16 pl[16];
#pragma unroll
  for (int j = 0; j < 4; ++j) {
    float4 v = *(const float4*)&src[j * 4];
    tile[lr][lc + j * 4 + 0] = v.x;
    tile[lr][lc + j * 4 + 1] = v.y;
    tile[lr][lc + j * 4 + 2] = v.z;
    tile[lr][lc + j * 4 + 3] = v.w;
    pl[j * 4 + 0] = f2bf(v.x); pl[j * 4 + 1] = f2bf(v.y);
    pl[j * 4 + 2] = f2bf(v.z); pl[j * 4 + 3] = f2bf(v.w);
  }
  u16* pdst = xb + (size_t)(t0 + lr) * 1024 + d0 + lc;
  *(uint4*)&pdst[0] = *(const uint4*)&pl[0];
  *(uint4*)&pdst[8] = *(const uint4*)&pl[8];
  __syncthreads();
  u16 tr[16];
#pragma unroll
  for (int j = 0; j < 16; ++j) tr[j] = f2bf(tile[lc + j][lr]);
  u16* tdst = xT + (size_t)(d0 + lr) * 16384 + t0 + lc;
  *(uint4*)&tdst[0] = *(const uint4*)&tr[0];
  *(uint4*)&tdst[8] = *(const uint4*)&tr[8];
}

// ------- plain cast of 3 weights (wq, wk, wv), each 1024x1024 -------
__global__ void cast_w_plain(const float* __restrict__ w0, const float* __restrict__ w1,
                             const float* __restrict__ w2, u16* __restrict__ out) {
  const float* w = blockIdx.z == 0 ? w0 : blockIdx.z == 1 ? w1 : w2;
  u16* o = out + (size_t)blockIdx.z * 1024 * 1024;
  long i = ((long)blockIdx.x * blockDim.x + threadIdx.x) * 8;
  float4 a = *(const float4*)&w[i];
  float4 b = *(const float4*)&w[i + 4];
  u16 p[8];
  p[0] = f2bf(a.x); p[1] = f2bf(a.y); p[2] = f2bf(a.z); p[3] = f2bf(a.w);
  p[4] = f2bf(b.x); p[5] = f2bf(b.y); p[6] = f2bf(b.z); p[7] = f2bf(b.w);
  *(uint4*)&o[i] = *(const uint4*)p;
}

// ------- transpose-cast: out[c][r] = in[r][c], 1024x1024 -------
__global__ __launch_bounds__(256) void cast_trans(const float* __restrict__ in,
                                                  u16* __restrict__ out) {
  __shared__ float tile[64][65];
  const int t = threadIdx.x;
  const int lr = t >> 2, lc = (t & 3) * 16;
  const int r0 = blockIdx.y * 64, c0 = blockIdx.x * 64;
  const float* src = in + (size_t)(r0 + lr) * 1024 + c0 + lc;
#pragma unroll
  for (int j = 0; j < 4; ++j) {
    float4 v = *(const float4*)&src[j * 4];
    tile[lr][lc + j * 4 + 0] = v.x;
    tile[lr][lc + j * 4 + 1] = v.y;
    tile[lr][lc + j * 4 + 2] = v.z;
    tile[lr][lc + j * 4 + 3] = v.w;
  }
  __syncthreads();
  u16 tr[16];
#pragma unroll
  for (int j = 0; j < 16; ++j) tr[j] = f2bf(tile[lc + j][lr]);
  u16* dst = out + (size_t)(c0 + lr) * 1024 + r0 + lc;
  *(uint4*)&dst[0] = *(const uint4*)&tr[0];
  *(uint4*)&dst[8] = *(const uint4*)&tr[8];
}

// ---------------- generic batched NT GEMM: C[M,N] = A[M,K] * B[N,K]^T --------
// 128x128 tile, BK=64, 256 threads (4 waves, 2x2), mfma_f32_16x16x32_bf16,
// global_load_lds width-16 staging, XOR-swizzled LDS (pre-swizzled source).
// blockIdx.z batches with element strides sA/sB/sC.
template <bool F32OUT>
__global__ __launch_bounds__(256) void gemm_bt(const u16* __restrict__ A,
                                               const u16* __restrict__ B,
                                               void* __restrict__ C,
                                               int lda, int ldb, int ldc, int K,
                                               size_t sA, size_t sB, size_t sC) {
  __shared__ u16 lds[2 * 8192];  // A tile [128][64] @0, B tile [128][64] @8192
  A += (size_t)blockIdx.z * sA;
  B += (size_t)blockIdx.z * sB;
  const int t = threadIdx.x;
  const int l = t & 63;
  const int w = t >> 6;
  const int wr = w >> 1, wc = w & 1;
  const int lr16 = l & 15, hi = l >> 4;
  const int mBase = blockIdx.y * 128;
  const int nBase = blockIdx.x * 128;

  f32x4 acc[4][4];
#pragma unroll
  for (int m = 0; m < 4; ++m)
#pragma unroll
    for (int n = 0; n < 4; ++n) acc[m][n] = (f32x4){0.f, 0.f, 0.f, 0.f};

  for (int kt = 0; kt < K; kt += 64) {
    __syncthreads();
#pragma unroll
    for (int i = 0; i < 4; ++i) {
      int s = i * 256 + t;
      int row = s >> 3, cp = s & 7;
      int clog = cp ^ (row & 7);
      const u16* g = A + (size_t)(mBase + row) * lda + kt + clog * 8;
      GLOAD16(g, &lds[s * 8]);
    }
#pragma unroll
    for (int i = 0; i < 4; ++i) {
      int s = i * 256 + t;
      int row = s >> 3, cp = s & 7;
      int clog = cp ^ (row & 7);
      const u16* g = B + (size_t)(nBase + row) * ldb + kt + clog * 8;
      GLOAD16(g, &lds[8192 + s * 8]);
    }
    asm volatile("s_waitcnt vmcnt(0)" ::: "memory");
    __syncthreads();
#pragma unroll
    for (int ks = 0; ks < 2; ++ks) {
      bf16x8 af[4], bfr[4];
#pragma unroll
      for (int m = 0; m < 4; ++m) {
        int row = wr * 64 + m * 16 + lr16;
        int p = (ks * 4 + hi) ^ (row & 7);
        af[m] = *(const bf16x8*)&lds[row * 64 + p * 8];
      }
#pragma unroll
      for (int n = 0; n < 4; ++n) {
        int row = wc * 64 + n * 16 + lr16;
        int p = (ks * 4 + hi) ^ (row & 7);
        bfr[n] = *(const bf16x8*)&lds[8192 + row * 64 + p * 8];
      }
#pragma unroll
      for (int m = 0; m < 4; ++m)
#pragma unroll
        for (int n = 0; n < 4; ++n)
          acc[m][n] = __builtin_amdgcn_mfma_f32_16x16x32_bf16(af[m], bfr[n], acc[m][n], 0, 0, 0);
    }
  }

  // epilogue: C/D layout col=lane&15, row=(lane>>4)*4+reg
#pragma unroll
  for (int m = 0; m < 4; ++m) {
    int row0 = mBase + wr * 64 + m * 16 + hi * 4;
#pragma unroll
    for (int n = 0; n < 4; ++n) {
      int col = nBase + wc * 64 + n * 16 + lr16;
      f32x4 v = acc[m][n];
      if (F32OUT) {
        float* Cf = (float*)C + (size_t)blockIdx.z * sC;
#pragma unroll
        for (int r = 0; r < 4; ++r) Cf[(size_t)(row0 + r) * ldc + col] = v[r];
      } else {
        u16* Cb = (u16*)C + (size_t)blockIdx.z * sC;
#pragma unroll
        for (int r = 0; r < 4; ++r) Cb[(size_t)(row0 + r) * ldc + col] = f2bf(v[r]);
      }
    }
  }
}

// ---------------- host-side orchestration ----------------
// out = x_b @ W1 @ G_b @ W2, with W1 = wq wk^T, W2 = wv wo, G_b = x_b^T x_b.
// All GEMMs in NT form (G symmetric; P produced transposed via PT = W2T G W1T).
extern "C" void kernel_launch(void* const* d_in, const int* in_sizes, int n_in,
                              void* d_out, int out_size, void* d_ws, size_t ws_size,
                              hipStream_t stream) {
  const float* x  = (const float*)d_in[0];
  const float* wq = (const float*)d_in[1];
  const float* wk = (const float*)d_in[2];
  const float* wv = (const float*)d_in[3];
  const float* wo = (const float*)d_in[4];
  float* out = (float*)d_out;

  u16* ws = (u16*)d_ws;
  const size_t MW = 1048576;  // 1024*1024
  u16* xb  = ws;                    // [16384][1024]
  u16* xT  = ws + 16777216;         // [1024][16384]
  u16* Wb  = ws + 33554432;         // wq, wk, wv plain (3 x MW)
  u16* woT = Wb + 3 * MW;           // wo transposed
  u16* W1  = woT + MW;              // wq @ wk^T
  u16* W2T = W1 + MW;               // (wv @ wo)^T
  u16* G   = W2T + MW;              // [4][1024][1024] Gram
  u16* S   = G + 4 * MW;            // [4] W2T @ G_b
  u16* PT  = S + 4 * MW;            // [4] P_b^T

  // casts
  cast_x_tr<<<dim3(16, 256), 256, 0, stream>>>(x, xb, xT);
  cast_w_plain<<<dim3(512, 1, 3), 256, 0, stream>>>(wq, wk, wv, Wb);
  cast_trans<<<dim3(16, 16), 256, 0, stream>>>(wo, woT);

  // W1 = NT(wq, wk): W1[d][e] = sum_f wq[d][f] wk[e][f]
  gemm_bt<false><<<dim3(8, 8), 256, 0, stream>>>(Wb + 0 * MW, Wb + 1 * MW, W1,
                                                 1024, 1024, 1024, 1024, 0, 0, 0);
  // W2T = NT(woT, wv): W2T[e][d] = sum_f wo[f][e] wv[d][f] = (wv@wo)^T
  gemm_bt<false><<<dim3(8, 8), 256, 0, stream>>>(woT, Wb + 2 * MW, W2T,
                                                 1024, 1024, 1024, 1024, 0, 0, 0);
  // G_b = NT(xT_b, xT_b), K=4096 (batch = column slice of xT)
  gemm_bt<false><<<dim3(8, 8, 4), 256, 0, stream>>>(xT, xT, G,
                                                    16384, 16384, 1024, 4096,
                                                    4096, 4096, MW);
  // S_b = NT(W2T, G_b) = W2^T @ G_b   (G symmetric)
  gemm_bt<false><<<dim3(8, 8, 4), 256, 0, stream>>>(W2T, G, S,
                                                    1024, 1024, 1024, 1024,
                                                    0, MW, MW);
  // PT_b = NT(S_b, W1) = S_b @ W1^T = P_b^T
  gemm_bt<false><<<dim3(8, 8, 4), 256, 0, stream>>>(S, W1, PT,
                                                    1024, 1024, 1024, 1024,
                                                    MW, 0, MW);
  // out_b = NT(xb_b, PT_b) = x_b @ P_b  (f32 output)
  gemm_bt<true><<<dim3(8, 32, 4), 256, 0, stream>>>(xb, PT, out,
                                                    1024, 1024, 1024, 1024,
                                                    (size_t)4096 * 1024, MW,
                                                    (size_t)4096 * 1024);
}

// Round 3
// 224.849 us; speedup vs baseline: 3.1836x; 1.0767x over previous
//
#include <hip/hip_runtime.h>
#include <hip/hip_bf16.h>
#include <stdint.h>

typedef unsigned short u16;
typedef short bf16x8 __attribute__((ext_vector_type(8)));
typedef float f32x4 __attribute__((ext_vector_type(4)));

#define GLOAD16(gp, lp) __builtin_amdgcn_global_load_lds( \
    (const __attribute__((address_space(1))) uint32_t*)(gp), \
    (__attribute__((address_space(3))) uint32_t*)(lp), 16, 0, 0)

__device__ __forceinline__ u16 f2bf(float f) {
  union { float f; uint32_t u; } x; x.f = f;
  return (u16)((x.u + 0x7FFFu + ((x.u >> 16) & 1u)) >> 16);
}

// ------- cast x: xb[t][d] bf16 (plain) AND xT[d][t] bf16 (transposed) -------
__global__ __launch_bounds__(256) void cast_x_tr(const float* __restrict__ x,
                                                 u16* __restrict__ xb,
                                                 u16* __restrict__ xT) {
  __shared__ float tile[64][65];
  const int t = threadIdx.x;
  const int lr = t >> 2, lc = (t & 3) * 16;
  const int d0 = blockIdx.x * 64;   // d tile (16)
  const int t0 = blockIdx.y * 64;   // token tile (256)
  const float* src = x + (size_t)(t0 + lr) * 1024 + d0 + lc;
  u16 pl[16];
#pragma unroll
  for (int j = 0; j < 4; ++j) {
    float4 v = *(const float4*)&src[j * 4];
    tile[lr][lc + j * 4 + 0] = v.x;
    tile[lr][lc + j * 4 + 1] = v.y;
    tile[lr][lc + j * 4 + 2] = v.z;
    tile[lr][lc + j * 4 + 3] = v.w;
    pl[j * 4 + 0] = f2bf(v.x); pl[j * 4 + 1] = f2bf(v.y);
    pl[j * 4 + 2] = f2bf(v.z); pl[j * 4 + 3] = f2bf(v.w);
  }
  u16* pdst = xb + (size_t)(t0 + lr) * 1024 + d0 + lc;
  *(uint4*)&pdst[0] = *(const uint4*)&pl[0];
  *(uint4*)&pdst[8] = *(const uint4*)&pl[8];
  __syncthreads();
  u16 tr[16];
#pragma unroll
  for (int j = 0; j < 16; ++j) tr[j] = f2bf(tile[lc + j][lr]);
  u16* tdst = xT + (size_t)(d0 + lr) * 16384 + t0 + lc;
  *(uint4*)&tdst[0] = *(const uint4*)&tr[0];
  *(uint4*)&tdst[8] = *(const uint4*)&tr[8];
}

// ------- plain cast of wq, wk, wv to explicit destinations -------
__global__ void cast_w_plain(const float* __restrict__ w0, const float* __restrict__ w1,
                             const float* __restrict__ w2,
                             u16* __restrict__ d0, u16* __restrict__ d1,
                             u16* __restrict__ d2) {
  const float* w = blockIdx.z == 0 ? w0 : blockIdx.z == 1 ? w1 : w2;
  u16* o = blockIdx.z == 0 ? d0 : blockIdx.z == 1 ? d1 : d2;
  long i = ((long)blockIdx.x * blockDim.x + threadIdx.x) * 8;
  float4 a = *(const float4*)&w[i];
  float4 b = *(const float4*)&w[i + 4];
  u16 p[8];
  p[0] = f2bf(a.x); p[1] = f2bf(a.y); p[2] = f2bf(a.z); p[3] = f2bf(a.w);
  p[4] = f2bf(b.x); p[5] = f2bf(b.y); p[6] = f2bf(b.z); p[7] = f2bf(b.w);
  *(uint4*)&o[i] = *(const uint4*)p;
}

// ------- transpose-cast: out[c][r] = in[r][c], 1024x1024 -------
__global__ __launch_bounds__(256) void cast_trans(const float* __restrict__ in,
                                                  u16* __restrict__ out) {
  __shared__ float tile[64][65];
  const int t = threadIdx.x;
  const int lr = t >> 2, lc = (t & 3) * 16;
  const int r0 = blockIdx.y * 64, c0 = blockIdx.x * 64;
  const float* src = in + (size_t)(r0 + lr) * 1024 + c0 + lc;
#pragma unroll
  for (int j = 0; j < 4; ++j) {
    float4 v = *(const float4*)&src[j * 4];
    tile[lr][lc + j * 4 + 0] = v.x;
    tile[lr][lc + j * 4 + 1] = v.y;
    tile[lr][lc + j * 4 + 2] = v.z;
    tile[lr][lc + j * 4 + 3] = v.w;
  }
  __syncthreads();
  u16 tr[16];
#pragma unroll
  for (int j = 0; j < 16; ++j) tr[j] = f2bf(tile[lc + j][lr]);
  u16* dst = out + (size_t)(c0 + lr) * 1024 + r0 + lc;
  *(uint4*)&dst[0] = *(const uint4*)&tr[0];
  *(uint4*)&dst[8] = *(const uint4*)&tr[8];
}

// ---------------- generic batched NT GEMM: C[M,N] = A[M,K] * B[N,K]^T --------
template <bool F32OUT>
__global__ __launch_bounds__(256) void gemm_bt(const u16* __restrict__ A,
                                               const u16* __restrict__ B,
                                               void* __restrict__ C,
                                               int lda, int ldb, int ldc, int K,
                                               size_t sA, size_t sB, size_t sC) {
  __shared__ u16 lds[2 * 8192];
  A += (size_t)blockIdx.z * sA;
  B += (size_t)blockIdx.z * sB;
  const int t = threadIdx.x;
  const int l = t & 63;
  const int w = t >> 6;
  const int wr = w >> 1, wc = w & 1;
  const int lr16 = l & 15, hi = l >> 4;
  const int mBase = blockIdx.y * 128;
  const int nBase = blockIdx.x * 128;

  f32x4 acc[4][4];
#pragma unroll
  for (int m = 0; m < 4; ++m)
#pragma unroll
    for (int n = 0; n < 4; ++n) acc[m][n] = (f32x4){0.f, 0.f, 0.f, 0.f};

  for (int kt = 0; kt < K; kt += 64) {
    __syncthreads();
#pragma unroll
    for (int i = 0; i < 4; ++i) {
      int s = i * 256 + t;
      int row = s >> 3, cp = s & 7;
      int clog = cp ^ (row & 7);
      const u16* g = A + (size_t)(mBase + row) * lda + kt + clog * 8;
      GLOAD16(g, &lds[s * 8]);
    }
#pragma unroll
    for (int i = 0; i < 4; ++i) {
      int s = i * 256 + t;
      int row = s >> 3, cp = s & 7;
      int clog = cp ^ (row & 7);
      const u16* g = B + (size_t)(nBase + row) * ldb + kt + clog * 8;
      GLOAD16(g, &lds[8192 + s * 8]);
    }
    asm volatile("s_waitcnt vmcnt(0)" ::: "memory");
    __syncthreads();
#pragma unroll
    for (int ks = 0; ks < 2; ++ks) {
      bf16x8 af[4], bfr[4];
#pragma unroll
      for (int m = 0; m < 4; ++m) {
        int row = wr * 64 + m * 16 + lr16;
        int p = (ks * 4 + hi) ^ (row & 7);
        af[m] = *(const bf16x8*)&lds[row * 64 + p * 8];
      }
#pragma unroll
      for (int n = 0; n < 4; ++n) {
        int row = wc * 64 + n * 16 + lr16;
        int p = (ks * 4 + hi) ^ (row & 7);
        bfr[n] = *(const bf16x8*)&lds[8192 + row * 64 + p * 8];
      }
#pragma unroll
      for (int m = 0; m < 4; ++m)
#pragma unroll
        for (int n = 0; n < 4; ++n)
          acc[m][n] = __builtin_amdgcn_mfma_f32_16x16x32_bf16(af[m], bfr[n], acc[m][n], 0, 0, 0);
    }
  }

#pragma unroll
  for (int m = 0; m < 4; ++m) {
    int row0 = mBase + wr * 64 + m * 16 + hi * 4;
#pragma unroll
    for (int n = 0; n < 4; ++n) {
      int col = nBase + wc * 64 + n * 16 + lr16;
      f32x4 v = acc[m][n];
      if (F32OUT) {
        float* Cf = (float*)C + (size_t)blockIdx.z * sC;
#pragma unroll
        for (int r = 0; r < 4; ++r) Cf[(size_t)(row0 + r) * ldc + col] = v[r];
      } else {
        u16* Cb = (u16*)C + (size_t)blockIdx.z * sC;
#pragma unroll
        for (int r = 0; r < 4; ++r) Cb[(size_t)(row0 + r) * ldc + col] = f2bf(v[r]);
      }
    }
  }
}

// ---------- split-K Gram: Gp[z] = xT_b[:, kc*1024:(kc+1)*1024] self-NT ----------
// z = b*4 + kc; output f32 partials [16][1024][1024].
__global__ __launch_bounds__(256) void gemm_gram_splitk(const u16* __restrict__ xT,
                                                        float* __restrict__ Gp) {
  __shared__ u16 lds[2 * 8192];
  const int z = blockIdx.z;
  const int b = z >> 2, kc = z & 3;
  const u16* A = xT + (size_t)b * 4096 + (size_t)kc * 1024;
  const int lda = 16384;
  const int t = threadIdx.x;
  const int l = t & 63;
  const int w = t >> 6;
  const int wr = w >> 1, wc = w & 1;
  const int lr16 = l & 15, hi = l >> 4;
  const int mBase = blockIdx.y * 128;
  const int nBase = blockIdx.x * 128;

  f32x4 acc[4][4];
#pragma unroll
  for (int m = 0; m < 4; ++m)
#pragma unroll
    for (int n = 0; n < 4; ++n) acc[m][n] = (f32x4){0.f, 0.f, 0.f, 0.f};

  for (int kt = 0; kt < 1024; kt += 64) {
    __syncthreads();
#pragma unroll
    for (int i = 0; i < 4; ++i) {
      int s = i * 256 + t;
      int row = s >> 3, cp = s & 7;
      int clog = cp ^ (row & 7);
      const u16* g = A + (size_t)(mBase + row) * lda + kt + clog * 8;
      GLOAD16(g, &lds[s * 8]);
    }
#pragma unroll
    for (int i = 0; i < 4; ++i) {
      int s = i * 256 + t;
      int row = s >> 3, cp = s & 7;
      int clog = cp ^ (row & 7);
      const u16* g = A + (size_t)(nBase + row) * lda + kt + clog * 8;
      GLOAD16(g, &lds[8192 + s * 8]);
    }
    asm volatile("s_waitcnt vmcnt(0)" ::: "memory");
    __syncthreads();
#pragma unroll
    for (int ks = 0; ks < 2; ++ks) {
      bf16x8 af[4], bfr[4];
#pragma unroll
      for (int m = 0; m < 4; ++m) {
        int row = wr * 64 + m * 16 + lr16;
        int p = (ks * 4 + hi) ^ (row & 7);
        af[m] = *(const bf16x8*)&lds[row * 64 + p * 8];
      }
#pragma unroll
      for (int n = 0; n < 4; ++n) {
        int row = wc * 64 + n * 16 + lr16;
        int p = (ks * 4 + hi) ^ (row & 7);
        bfr[n] = *(const bf16x8*)&lds[8192 + row * 64 + p * 8];
      }
#pragma unroll
      for (int m = 0; m < 4; ++m)
#pragma unroll
        for (int n = 0; n < 4; ++n)
          acc[m][n] = __builtin_amdgcn_mfma_f32_16x16x32_bf16(af[m], bfr[n], acc[m][n], 0, 0, 0);
    }
  }

  float* Cf = Gp + (size_t)z * 1048576;
#pragma unroll
  for (int m = 0; m < 4; ++m) {
    int row0 = mBase + wr * 64 + m * 16 + hi * 4;
#pragma unroll
    for (int n = 0; n < 4; ++n) {
      int col = nBase + wc * 64 + n * 16 + lr16;
      f32x4 v = acc[m][n];
#pragma unroll
      for (int r = 0; r < 4; ++r) Cf[(size_t)(row0 + r) * 1024 + col] = v[r];
    }
  }
}

// ---------- reduce 4 f32 partials -> bf16 G ----------
__global__ void reduce_gram(const float* __restrict__ Gp, u16* __restrict__ G) {
  const size_t MW = 1048576;
  int b = blockIdx.y;
  size_t i = ((size_t)blockIdx.x * 256 + threadIdx.x) * 4;
  const float* p = Gp + (size_t)b * 4 * MW + i;
  float4 s0 = *(const float4*)&p[0];
  float4 s1 = *(const float4*)&p[MW];
  float4 s2 = *(const float4*)&p[2 * MW];
  float4 s3 = *(const float4*)&p[3 * MW];
  u16 o[4];
  o[0] = f2bf(s0.x + s1.x + s2.x + s3.x);
  o[1] = f2bf(s0.y + s1.y + s2.y + s3.y);
  o[2] = f2bf(s0.z + s1.z + s2.z + s3.z);
  o[3] = f2bf(s0.w + s1.w + s2.w + s3.w);
  *(uint64_t*)&G[b * MW + i] = *(const uint64_t*)o;
}

// ---------------- host-side orchestration ----------------
// out_b = x_b @ W1 @ G_b @ W2 ; W1 = wq wk^T, W2 = wv wo, G_b = x_b^T x_b.
extern "C" void kernel_launch(void* const* d_in, const int* in_sizes, int n_in,
                              void* d_out, int out_size, void* d_ws, size_t ws_size,
                              hipStream_t stream) {
  const float* x  = (const float*)d_in[0];
  const float* wq = (const float*)d_in[1];
  const float* wk = (const float*)d_in[2];
  const float* wv = (const float*)d_in[3];
  const float* wo = (const float*)d_in[4];
  float* out = (float*)d_out;

  u16* ws = (u16*)d_ws;
  const size_t MW = 1048576;
  u16* xb  = ws;                    // [16384][1024]
  u16* xT  = ws + 16 * MW;          // [1024][16384]
  u16* WA  = ws + 32 * MW;          // [wq][woT]     (A operands of merged GEMM)
  u16* WBb = ws + 34 * MW;          // [wk][wv]      (B operands)
  u16* W12 = ws + 36 * MW;          // [W1][W2T]
  u16* G   = ws + 38 * MW;          // [4][1024][1024]
  u16* S   = ws + 42 * MW;          // [4]
  u16* PT  = ws + 46 * MW;          // [4]
  float* Gp = (float*)(ws + 50 * MW);  // [16][1024][1024] f32 partials (64 MB)

  // casts
  cast_x_tr<<<dim3(16, 256), 256, 0, stream>>>(x, xb, xT);
  cast_w_plain<<<dim3(512, 1, 3), 256, 0, stream>>>(wq, wk, wv,
                                                    WA, WBb, WBb + MW);
  cast_trans<<<dim3(16, 16), 256, 0, stream>>>(wo, WA + MW);

  // merged: W1 = NT(wq, wk), W2T = NT(woT, wv)
  gemm_bt<false><<<dim3(8, 8, 2), 256, 0, stream>>>(WA, WBb, W12,
                                                    1024, 1024, 1024, 1024,
                                                    MW, MW, MW);
  // Gram split-K: Gp[b*4+kc] = partial(x_b^T x_b)
  gemm_gram_splitk<<<dim3(8, 8, 16), 256, 0, stream>>>(xT, Gp);
  reduce_gram<<<dim3(1024, 4), 256, 0, stream>>>(Gp, G);

  // S_b = NT(W2T, G_b) = W2^T @ G_b   (G symmetric)
  gemm_bt<false><<<dim3(8, 8, 4), 256, 0, stream>>>(W12 + MW, G, S,
                                                    1024, 1024, 1024, 1024,
                                                    0, MW, MW);
  // PT_b = NT(S_b, W1) = S_b @ W1^T
  gemm_bt<false><<<dim3(8, 8, 4), 256, 0, stream>>>(S, W12, PT,
                                                    1024, 1024, 1024, 1024,
                                                    MW, 0, MW);
  // out_b = NT(xb_b, PT_b) = x_b @ P_b  (f32 output)
  gemm_bt<true><<<dim3(8, 32, 4), 256, 0, stream>>>(xb, PT, out,
                                                    1024, 1024, 1024, 1024,
                                                    (size_t)4096 * 1024, MW,
                                                    (size_t)4096 * 1024);
}

// Round 4
// 208.115 us; speedup vs baseline: 3.4396x; 1.0804x over previous
//
#include <hip/hip_runtime.h>
#include <hip/hip_bf16.h>
#include <stdint.h>

typedef unsigned short u16;
typedef short bf16x8 __attribute__((ext_vector_type(8)));
typedef float f32x4 __attribute__((ext_vector_type(4)));

#define GLOAD16(gp, lp) __builtin_amdgcn_global_load_lds( \
    (const __attribute__((address_space(1))) uint32_t*)(gp), \
    (__attribute__((address_space(3))) uint32_t*)(lp), 16, 0, 0)

__device__ __forceinline__ u16 f2bf(float f) {
  union { float f; uint32_t u; } x; x.f = f;
  return (u16)((x.u + 0x7FFFu + ((x.u >> 16) & 1u)) >> 16);
}

// Bijective XCD-chunked block swizzle (T1, m204 form). Requires nwg % 8 == 0.
// HW round-robins consecutive linear ids across XCDs; this gives each XCD a
// contiguous chunk of work ids so data-sharing neighbor blocks share an L2.
__device__ __forceinline__ void xcd_swizzle(int& bx, int& by, int& bz) {
  const int gx = gridDim.x, gy = gridDim.y;
  const int nwg = gx * gy * (int)gridDim.z;
  const int lin = ((int)blockIdx.z * gy + (int)blockIdx.y) * gx + (int)blockIdx.x;
  const int q = nwg >> 3;
  const int wl = (lin & 7) * q + (lin >> 3);
  bz = wl / (gx * gy);
  const int rem = wl - bz * gx * gy;
  by = rem / gx;
  bx = rem - by * gx;
}

// ------- cast x: xb[t][d] bf16 (plain) AND xT[d][t] bf16 (transposed) -------
__global__ __launch_bounds__(256) void cast_x_tr(const float* __restrict__ x,
                                                 u16* __restrict__ xb,
                                                 u16* __restrict__ xT) {
  __shared__ float tile[64][65];
  const int t = threadIdx.x;
  const int lr = t >> 2, lc = (t & 3) * 16;
  const int d0 = blockIdx.x * 64;   // d tile (16)
  const int t0 = blockIdx.y * 64;   // token tile (256)
  const float* src = x + (size_t)(t0 + lr) * 1024 + d0 + lc;
  u16 pl[16];
#pragma unroll
  for (int j = 0; j < 4; ++j) {
    float4 v = *(const float4*)&src[j * 4];
    tile[lr][lc + j * 4 + 0] = v.x;
    tile[lr][lc + j * 4 + 1] = v.y;
    tile[lr][lc + j * 4 + 2] = v.z;
    tile[lr][lc + j * 4 + 3] = v.w;
    pl[j * 4 + 0] = f2bf(v.x); pl[j * 4 + 1] = f2bf(v.y);
    pl[j * 4 + 2] = f2bf(v.z); pl[j * 4 + 3] = f2bf(v.w);
  }
  u16* pdst = xb + (size_t)(t0 + lr) * 1024 + d0 + lc;
  *(uint4*)&pdst[0] = *(const uint4*)&pl[0];
  *(uint4*)&pdst[8] = *(const uint4*)&pl[8];
  __syncthreads();
  u16 tr[16];
#pragma unroll
  for (int j = 0; j < 16; ++j) tr[j] = f2bf(tile[lc + j][lr]);
  u16* tdst = xT + (size_t)(d0 + lr) * 16384 + t0 + lc;
  *(uint4*)&tdst[0] = *(const uint4*)&tr[0];
  *(uint4*)&tdst[8] = *(const uint4*)&tr[8];
}

// ------- plain cast of wq, wk, wv to explicit destinations -------
__global__ void cast_w_plain(const float* __restrict__ w0, const float* __restrict__ w1,
                             const float* __restrict__ w2,
                             u16* __restrict__ d0, u16* __restrict__ d1,
                             u16* __restrict__ d2) {
  const float* w = blockIdx.z == 0 ? w0 : blockIdx.z == 1 ? w1 : w2;
  u16* o = blockIdx.z == 0 ? d0 : blockIdx.z == 1 ? d1 : d2;
  long i = ((long)blockIdx.x * blockDim.x + threadIdx.x) * 8;
  float4 a = *(const float4*)&w[i];
  float4 b = *(const float4*)&w[i + 4];
  u16 p[8];
  p[0] = f2bf(a.x); p[1] = f2bf(a.y); p[2] = f2bf(a.z); p[3] = f2bf(a.w);
  p[4] = f2bf(b.x); p[5] = f2bf(b.y); p[6] = f2bf(b.z); p[7] = f2bf(b.w);
  *(uint4*)&o[i] = *(const uint4*)p;
}

// ------- transpose-cast: out[c][r] = in[r][c], 1024x1024 -------
__global__ __launch_bounds__(256) void cast_trans(const float* __restrict__ in,
                                                  u16* __restrict__ out) {
  __shared__ float tile[64][65];
  const int t = threadIdx.x;
  const int lr = t >> 2, lc = (t & 3) * 16;
  const int r0 = blockIdx.y * 64, c0 = blockIdx.x * 64;
  const float* src = in + (size_t)(r0 + lr) * 1024 + c0 + lc;
#pragma unroll
  for (int j = 0; j < 4; ++j) {
    float4 v = *(const float4*)&src[j * 4];
    tile[lr][lc + j * 4 + 0] = v.x;
    tile[lr][lc + j * 4 + 1] = v.y;
    tile[lr][lc + j * 4 + 2] = v.z;
    tile[lr][lc + j * 4 + 3] = v.w;
  }
  __syncthreads();
  u16 tr[16];
#pragma unroll
  for (int j = 0; j < 16; ++j) tr[j] = f2bf(tile[lc + j][lr]);
  u16* dst = out + (size_t)(c0 + lr) * 1024 + r0 + lc;
  *(uint4*)&dst[0] = *(const uint4*)&tr[0];
  *(uint4*)&dst[8] = *(const uint4*)&tr[8];
}

// ---------------- generic batched NT GEMM: C[M,N] = A[M,K] * B[N,K]^T --------
template <bool F32OUT>
__global__ __launch_bounds__(256) void gemm_bt(const u16* __restrict__ A,
                                               const u16* __restrict__ B,
                                               void* __restrict__ C,
                                               int lda, int ldb, int ldc, int K,
                                               size_t sA, size_t sB, size_t sC) {
  __shared__ u16 lds[2 * 8192];
  int bx, by, bz;
  xcd_swizzle(bx, by, bz);
  A += (size_t)bz * sA;
  B += (size_t)bz * sB;
  const int t = threadIdx.x;
  const int l = t & 63;
  const int w = t >> 6;
  const int wr = w >> 1, wc = w & 1;
  const int lr16 = l & 15, hi = l >> 4;
  const int mBase = by * 128;
  const int nBase = bx * 128;

  f32x4 acc[4][4];
#pragma unroll
  for (int m = 0; m < 4; ++m)
#pragma unroll
    for (int n = 0; n < 4; ++n) acc[m][n] = (f32x4){0.f, 0.f, 0.f, 0.f};

  for (int kt = 0; kt < K; kt += 64) {
    __syncthreads();
#pragma unroll
    for (int i = 0; i < 4; ++i) {
      int s = i * 256 + t;
      int row = s >> 3, cp = s & 7;
      int clog = cp ^ (row & 7);
      const u16* g = A + (size_t)(mBase + row) * lda + kt + clog * 8;
      GLOAD16(g, &lds[s * 8]);
    }
#pragma unroll
    for (int i = 0; i < 4; ++i) {
      int s = i * 256 + t;
      int row = s >> 3, cp = s & 7;
      int clog = cp ^ (row & 7);
      const u16* g = B + (size_t)(nBase + row) * ldb + kt + clog * 8;
      GLOAD16(g, &lds[8192 + s * 8]);
    }
    asm volatile("s_waitcnt vmcnt(0)" ::: "memory");
    __syncthreads();
#pragma unroll
    for (int ks = 0; ks < 2; ++ks) {
      bf16x8 af[4], bfr[4];
#pragma unroll
      for (int m = 0; m < 4; ++m) {
        int row = wr * 64 + m * 16 + lr16;
        int p = (ks * 4 + hi) ^ (row & 7);
        af[m] = *(const bf16x8*)&lds[row * 64 + p * 8];
      }
#pragma unroll
      for (int n = 0; n < 4; ++n) {
        int row = wc * 64 + n * 16 + lr16;
        int p = (ks * 4 + hi) ^ (row & 7);
        bfr[n] = *(const bf16x8*)&lds[8192 + row * 64 + p * 8];
      }
#pragma unroll
      for (int m = 0; m < 4; ++m)
#pragma unroll
        for (int n = 0; n < 4; ++n)
          acc[m][n] = __builtin_amdgcn_mfma_f32_16x16x32_bf16(af[m], bfr[n], acc[m][n], 0, 0, 0);
    }
  }

#pragma unroll
  for (int m = 0; m < 4; ++m) {
    int row0 = mBase + wr * 64 + m * 16 + hi * 4;
#pragma unroll
    for (int n = 0; n < 4; ++n) {
      int col = nBase + wc * 64 + n * 16 + lr16;
      f32x4 v = acc[m][n];
      if (F32OUT) {
        float* Cf = (float*)C + (size_t)bz * sC;
#pragma unroll
        for (int r = 0; r < 4; ++r) Cf[(size_t)(row0 + r) * ldc + col] = v[r];
      } else {
        u16* Cb = (u16*)C + (size_t)bz * sC;
#pragma unroll
        for (int r = 0; r < 4; ++r) Cb[(size_t)(row0 + r) * ldc + col] = f2bf(v[r]);
      }
    }
  }
}

// ---------- split-K Gram: Gp[z] = xT_b[:, kc*1024:(kc+1)*1024] self-NT ----------
// z = b*4 + kc; output f32 partials [16][1024][1024].
__global__ __launch_bounds__(256) void gemm_gram_splitk(const u16* __restrict__ xT,
                                                        float* __restrict__ Gp) {
  __shared__ u16 lds[2 * 8192];
  int bx, by, bz;
  xcd_swizzle(bx, by, bz);
  const int b = bz >> 2, kc = bz & 3;
  const u16* A = xT + (size_t)b * 4096 + (size_t)kc * 1024;
  const int lda = 16384;
  const int t = threadIdx.x;
  const int l = t & 63;
  const int w = t >> 6;
  const int wr = w >> 1, wc = w & 1;
  const int lr16 = l & 15, hi = l >> 4;
  const int mBase = by * 128;
  const int nBase = bx * 128;

  f32x4 acc[4][4];
#pragma unroll
  for (int m = 0; m < 4; ++m)
#pragma unroll
    for (int n = 0; n < 4; ++n) acc[m][n] = (f32x4){0.f, 0.f, 0.f, 0.f};

  for (int kt = 0; kt < 1024; kt += 64) {
    __syncthreads();
#pragma unroll
    for (int i = 0; i < 4; ++i) {
      int s = i * 256 + t;
      int row = s >> 3, cp = s & 7;
      int clog = cp ^ (row & 7);
      const u16* g = A + (size_t)(mBase + row) * lda + kt + clog * 8;
      GLOAD16(g, &lds[s * 8]);
    }
#pragma unroll
    for (int i = 0; i < 4; ++i) {
      int s = i * 256 + t;
      int row = s >> 3, cp = s & 7;
      int clog = cp ^ (row & 7);
      const u16* g = A + (size_t)(nBase + row) * lda + kt + clog * 8;
      GLOAD16(g, &lds[8192 + s * 8]);
    }
    asm volatile("s_waitcnt vmcnt(0)" ::: "memory");
    __syncthreads();
#pragma unroll
    for (int ks = 0; ks < 2; ++ks) {
      bf16x8 af[4], bfr[4];
#pragma unroll
      for (int m = 0; m < 4; ++m) {
        int row = wr * 64 + m * 16 + lr16;
        int p = (ks * 4 + hi) ^ (row & 7);
        af[m] = *(const bf16x8*)&lds[row * 64 + p * 8];
      }
#pragma unroll
      for (int n = 0; n < 4; ++n) {
        int row = wc * 64 + n * 16 + lr16;
        int p = (ks * 4 + hi) ^ (row & 7);
        bfr[n] = *(const bf16x8*)&lds[8192 + row * 64 + p * 8];
      }
#pragma unroll
      for (int m = 0; m < 4; ++m)
#pragma unroll
        for (int n = 0; n < 4; ++n)
          acc[m][n] = __builtin_amdgcn_mfma_f32_16x16x32_bf16(af[m], bfr[n], acc[m][n], 0, 0, 0);
    }
  }

  float* Cf = Gp + (size_t)bz * 1048576;
#pragma unroll
  for (int m = 0; m < 4; ++m) {
    int row0 = mBase + wr * 64 + m * 16 + hi * 4;
#pragma unroll
    for (int n = 0; n < 4; ++n) {
      int col = nBase + wc * 64 + n * 16 + lr16;
      f32x4 v = acc[m][n];
#pragma unroll
      for (int r = 0; r < 4; ++r) Cf[(size_t)(row0 + r) * 1024 + col] = v[r];
    }
  }
}

// ---------- reduce 4 f32 partials -> bf16 G ----------
__global__ void reduce_gram(const float* __restrict__ Gp, u16* __restrict__ G) {
  const size_t MW = 1048576;
  int b = blockIdx.y;
  size_t i = ((size_t)blockIdx.x * 256 + threadIdx.x) * 4;
  const float* p = Gp + (size_t)b * 4 * MW + i;
  float4 s0 = *(const float4*)&p[0];
  float4 s1 = *(const float4*)&p[MW];
  float4 s2 = *(const float4*)&p[2 * MW];
  float4 s3 = *(const float4*)&p[3 * MW];
  u16 o[4];
  o[0] = f2bf(s0.x + s1.x + s2.x + s3.x);
  o[1] = f2bf(s0.y + s1.y + s2.y + s3.y);
  o[2] = f2bf(s0.z + s1.z + s2.z + s3.z);
  o[3] = f2bf(s0.w + s1.w + s2.w + s3.w);
  *(uint64_t*)&G[b * MW + i] = *(const uint64_t*)o;
}

// ---------------- host-side orchestration ----------------
// out_b = x_b @ W1 @ G_b @ W2 ; W1 = wq wk^T, W2 = wv wo, G_b = x_b^T x_b.
extern "C" void kernel_launch(void* const* d_in, const int* in_sizes, int n_in,
                              void* d_out, int out_size, void* d_ws, size_t ws_size,
                              hipStream_t stream) {
  const float* x  = (const float*)d_in[0];
  const float* wq = (const float*)d_in[1];
  const float* wk = (const float*)d_in[2];
  const float* wv = (const float*)d_in[3];
  const float* wo = (const float*)d_in[4];
  float* out = (float*)d_out;

  u16* ws = (u16*)d_ws;
  const size_t MW = 1048576;
  u16* xb  = ws;                    // [16384][1024]
  u16* xT  = ws + 16 * MW;          // [1024][16384]
  u16* WA  = ws + 32 * MW;          // [wq][woT]     (A operands of merged GEMM)
  u16* WBb = ws + 34 * MW;          // [wk][wv]      (B operands)
  u16* W12 = ws + 36 * MW;          // [W1][W2T]
  u16* G   = ws + 38 * MW;          // [4][1024][1024]
  u16* S   = ws + 42 * MW;          // [4]
  u16* PT  = ws + 46 * MW;          // [4]
  float* Gp = (float*)(ws + 50 * MW);  // [16][1024][1024] f32 partials (64 MB)

  // casts
  cast_x_tr<<<dim3(16, 256), 256, 0, stream>>>(x, xb, xT);
  cast_w_plain<<<dim3(512, 1, 3), 256, 0, stream>>>(wq, wk, wv,
                                                    WA, WBb, WBb + MW);
  cast_trans<<<dim3(16, 16), 256, 0, stream>>>(wo, WA + MW);

  // merged: W1 = NT(wq, wk), W2T = NT(woT, wv)
  gemm_bt<false><<<dim3(8, 8, 2), 256, 0, stream>>>(WA, WBb, W12,
                                                    1024, 1024, 1024, 1024,
                                                    MW, MW, MW);
  // Gram split-K: Gp[b*4+kc] = partial(x_b^T x_b)
  gemm_gram_splitk<<<dim3(8, 8, 16), 256, 0, stream>>>(xT, Gp);
  reduce_gram<<<dim3(1024, 4), 256, 0, stream>>>(Gp, G);

  // S_b = NT(W2T, G_b) = W2^T @ G_b   (G symmetric)
  gemm_bt<false><<<dim3(8, 8, 4), 256, 0, stream>>>(W12 + MW, G, S,
                                                    1024, 1024, 1024, 1024,
                                                    0, MW, MW);
  // PT_b = NT(S_b, W1) = S_b @ W1^T
  gemm_bt<false><<<dim3(8, 8, 4), 256, 0, stream>>>(S, W12, PT,
                                                    1024, 1024, 1024, 1024,
                                                    MW, 0, MW);
  // out_b = NT(xb_b, PT_b) = x_b @ P_b  (f32 output)
  gemm_bt<true><<<dim3(8, 32, 4), 256, 0, stream>>>(xb, PT, out,
                                                    1024, 1024, 1024, 1024,
                                                    (size_t)4096 * 1024, MW,
                                                    (size_t)4096 * 1024);
}

// Round 5
// 193.944 us; speedup vs baseline: 3.6909x; 1.0731x over previous
//
#include <hip/hip_runtime.h>
#include <hip/hip_bf16.h>
#include <stdint.h>

typedef unsigned short u16;
typedef short bf16x8 __attribute__((ext_vector_type(8)));
typedef float f32x4 __attribute__((ext_vector_type(4)));

#define GLOAD16(gp, lp) __builtin_amdgcn_global_load_lds( \
    (const __attribute__((address_space(1))) uint32_t*)(gp), \
    (__attribute__((address_space(3))) uint32_t*)(lp), 16, 0, 0)

#define VMCNT10 do { asm volatile("s_waitcnt vmcnt(10)" ::: "memory"); \
                     __builtin_amdgcn_sched_barrier(0); } while (0)
#define SBAR    do { __builtin_amdgcn_s_barrier(); \
                     __builtin_amdgcn_sched_barrier(0); } while (0)
#define LGKM0   do { asm volatile("s_waitcnt lgkmcnt(0)" ::: "memory"); \
                     __builtin_amdgcn_sched_barrier(0); } while (0)

__device__ __forceinline__ u16 f2bf(float f) {
  union { float f; uint32_t u; } x; x.f = f;
  return (u16)((x.u + 0x7FFFu + ((x.u >> 16) & 1u)) >> 16);
}

// Bijective XCD-chunked block swizzle (T1, m204 form). Requires nwg % 8 == 0.
__device__ __forceinline__ void xcd_swizzle(int& bx, int& by, int& bz) {
  const int gx = gridDim.x, gy = gridDim.y;
  const int nwg = gx * gy * (int)gridDim.z;
  const int lin = ((int)blockIdx.z * gy + (int)blockIdx.y) * gx + (int)blockIdx.x;
  const int q = nwg >> 3;
  const int wl = (lin & 7) * q + (lin >> 3);
  bz = wl / (gx * gy);
  const int rem = wl - bz * gx * gy;
  by = rem / gx;
  bx = rem - by * gx;
}

// ------- cast x: xb[t][d] bf16 (plain) AND xT[d][t] bf16 (transposed) -------
__global__ __launch_bounds__(256) void cast_x_tr(const float* __restrict__ x,
                                                 u16* __restrict__ xb,
                                                 u16* __restrict__ xT) {
  __shared__ float tile[64][65];
  const int t = threadIdx.x;
  const int lr = t >> 2, lc = (t & 3) * 16;
  const int d0 = blockIdx.x * 64;
  const int t0 = blockIdx.y * 64;
  const float* src = x + (size_t)(t0 + lr) * 1024 + d0 + lc;
  u16 pl[16];
#pragma unroll
  for (int j = 0; j < 4; ++j) {
    float4 v = *(const float4*)&src[j * 4];
    tile[lr][lc + j * 4 + 0] = v.x;
    tile[lr][lc + j * 4 + 1] = v.y;
    tile[lr][lc + j * 4 + 2] = v.z;
    tile[lr][lc + j * 4 + 3] = v.w;
    pl[j * 4 + 0] = f2bf(v.x); pl[j * 4 + 1] = f2bf(v.y);
    pl[j * 4 + 2] = f2bf(v.z); pl[j * 4 + 3] = f2bf(v.w);
  }
  u16* pdst = xb + (size_t)(t0 + lr) * 1024 + d0 + lc;
  *(uint4*)&pdst[0] = *(const uint4*)&pl[0];
  *(uint4*)&pdst[8] = *(const uint4*)&pl[8];
  __syncthreads();
  u16 tr[16];
#pragma unroll
  for (int j = 0; j < 16; ++j) tr[j] = f2bf(tile[lc + j][lr]);
  u16* tdst = xT + (size_t)(d0 + lr) * 16384 + t0 + lc;
  *(uint4*)&tdst[0] = *(const uint4*)&tr[0];
  *(uint4*)&tdst[8] = *(const uint4*)&tr[8];
}

// ------- plain cast of wq, wk, wv -------
__global__ void cast_w_plain(const float* __restrict__ w0, const float* __restrict__ w1,
                             const float* __restrict__ w2,
                             u16* __restrict__ d0, u16* __restrict__ d1,
                             u16* __restrict__ d2) {
  const float* w = blockIdx.z == 0 ? w0 : blockIdx.z == 1 ? w1 : w2;
  u16* o = blockIdx.z == 0 ? d0 : blockIdx.z == 1 ? d1 : d2;
  long i = ((long)blockIdx.x * blockDim.x + threadIdx.x) * 8;
  float4 a = *(const float4*)&w[i];
  float4 b = *(const float4*)&w[i + 4];
  u16 p[8];
  p[0] = f2bf(a.x); p[1] = f2bf(a.y); p[2] = f2bf(a.z); p[3] = f2bf(a.w);
  p[4] = f2bf(b.x); p[5] = f2bf(b.y); p[6] = f2bf(b.z); p[7] = f2bf(b.w);
  *(uint4*)&o[i] = *(const uint4*)p;
}

// ------- transpose-cast: out[c][r] = in[r][c], 1024x1024 -------
__global__ __launch_bounds__(256) void cast_trans(const float* __restrict__ in,
                                                  u16* __restrict__ out) {
  __shared__ float tile[64][65];
  const int t = threadIdx.x;
  const int lr = t >> 2, lc = (t & 3) * 16;
  const int r0 = blockIdx.y * 64, c0 = blockIdx.x * 64;
  const float* src = in + (size_t)(r0 + lr) * 1024 + c0 + lc;
#pragma unroll
  for (int j = 0; j < 4; ++j) {
    float4 v = *(const float4*)&src[j * 4];
    tile[lr][lc + j * 4 + 0] = v.x;
    tile[lr][lc + j * 4 + 1] = v.y;
    tile[lr][lc + j * 4 + 2] = v.z;
    tile[lr][lc + j * 4 + 3] = v.w;
  }
  __syncthreads();
  u16 tr[16];
#pragma unroll
  for (int j = 0; j < 16; ++j) tr[j] = f2bf(tile[lc + j][lr]);
  u16* dst = out + (size_t)(c0 + lr) * 1024 + r0 + lc;
  *(uint4*)&dst[0] = *(const uint4*)&tr[0];
  *(uint4*)&dst[8] = *(const uint4*)&tr[8];
}

// ---------------- 128^2 batched NT GEMM (small matrices) --------
template <bool F32OUT>
__global__ __launch_bounds__(256) void gemm_bt(const u16* __restrict__ A,
                                               const u16* __restrict__ B,
                                               void* __restrict__ C,
                                               int lda, int ldb, int ldc, int K,
                                               size_t sA, size_t sB, size_t sC) {
  __shared__ u16 lds[2 * 8192];
  int bx, by, bz;
  xcd_swizzle(bx, by, bz);
  A += (size_t)bz * sA;
  B += (size_t)bz * sB;
  const int t = threadIdx.x;
  const int l = t & 63;
  const int w = t >> 6;
  const int wr = w >> 1, wc = w & 1;
  const int lr16 = l & 15, hi = l >> 4;
  const int mBase = by * 128;
  const int nBase = bx * 128;

  f32x4 acc[4][4];
#pragma unroll
  for (int m = 0; m < 4; ++m)
#pragma unroll
    for (int n = 0; n < 4; ++n) acc[m][n] = (f32x4){0.f, 0.f, 0.f, 0.f};

  for (int kt = 0; kt < K; kt += 64) {
    __syncthreads();
#pragma unroll
    for (int i = 0; i < 4; ++i) {
      int s = i * 256 + t;
      int row = s >> 3, cp = s & 7;
      int clog = cp ^ (row & 7);
      const u16* g = A + (size_t)(mBase + row) * lda + kt + clog * 8;
      GLOAD16(g, &lds[s * 8]);
    }
#pragma unroll
    for (int i = 0; i < 4; ++i) {
      int s = i * 256 + t;
      int row = s >> 3, cp = s & 7;
      int clog = cp ^ (row & 7);
      const u16* g = B + (size_t)(nBase + row) * ldb + kt + clog * 8;
      GLOAD16(g, &lds[8192 + s * 8]);
    }
    asm volatile("s_waitcnt vmcnt(0)" ::: "memory");
    __syncthreads();
#pragma unroll
    for (int ks = 0; ks < 2; ++ks) {
      bf16x8 af[4], bfr[4];
#pragma unroll
      for (int m = 0; m < 4; ++m) {
        int row = wr * 64 + m * 16 + lr16;
        int p = (ks * 4 + hi) ^ (row & 7);
        af[m] = *(const bf16x8*)&lds[row * 64 + p * 8];
      }
#pragma unroll
      for (int n = 0; n < 4; ++n) {
        int row = wc * 64 + n * 16 + lr16;
        int p = (ks * 4 + hi) ^ (row & 7);
        bfr[n] = *(const bf16x8*)&lds[8192 + row * 64 + p * 8];
      }
#pragma unroll
      for (int m = 0; m < 4; ++m)
#pragma unroll
        for (int n = 0; n < 4; ++n)
          acc[m][n] = __builtin_amdgcn_mfma_f32_16x16x32_bf16(af[m], bfr[n], acc[m][n], 0, 0, 0);
    }
  }

#pragma unroll
  for (int m = 0; m < 4; ++m) {
    int row0 = mBase + wr * 64 + m * 16 + hi * 4;
#pragma unroll
    for (int n = 0; n < 4; ++n) {
      int col = nBase + wc * 64 + n * 16 + lr16;
      f32x4 v = acc[m][n];
      if (F32OUT) {
        float* Cf = (float*)C + (size_t)bz * sC;
#pragma unroll
        for (int r = 0; r < 4; ++r) Cf[(size_t)(row0 + r) * ldc + col] = v[r];
      } else {
        u16* Cb = (u16*)C + (size_t)bz * sC;
#pragma unroll
        for (int r = 0; r < 4; ++r) Cb[(size_t)(row0 + r) * ldc + col] = f2bf(v[r]);
      }
    }
  }
}

// =================== 256^2 8-phase NT GEMM core (f32 out) ===================
// BM=BN=256, BK=64, 512 thr (8 waves 2Mx4N). LDS: 2 buf x (A 256x64 | B 256x64).
// Frag rows: A(m)=(m>>2)*128+wr*64+(m&3)*16 ; B(n)=(n>>1)*128+wc*32+(n&1)*16
// -> each phase reads exactly one contiguous 128-row half of A or B.
// Stage schedule (one half/phase): p1->A1(t+1), p2->B0(t+2), p3->A0(t+2),
// p4->B1(t+2); steady-state counted wait = vmcnt(10) at p1..p3.
__device__ __forceinline__ void gemm256_core(const u16* __restrict__ A,
                                             const u16* __restrict__ B,
                                             float* __restrict__ C,
                                             int lda, int ldb, int ldc, int K,
                                             int mBase, int nBase, u16* lds) {
  const int t = threadIdx.x;
  const int l = t & 63;
  const int wid = t >> 6;
  const int wr = wid >> 2;          // 0..1
  const int wc = wid & 3;           // 0..3
  const int lr16 = l & 15, hi = l >> 4;
  // staging per-thread constants (slot s = g*512+t; row=s>>3, chunk=t&7)
  const int rl0 = t >> 3;           // rows 0..63   (g=0)
  const int rl1 = rl0 + 64;         // rows 64..127 (g=1)
  const int cp  = t & 7;
  const int cs  = cp ^ (rl0 & 7);   // pre-swizzled source chunk (same for rl1)
  const int NT = K >> 6;

  f32x4 acc[8][4];
#pragma unroll
  for (int m = 0; m < 8; ++m)
#pragma unroll
    for (int n = 0; n < 4; ++n) acc[m][n] = (f32x4){0.f, 0.f, 0.f, 0.f};

  auto stage = [&](const u16* g0, int ld, u16* d) {
    GLOAD16(g0 + (size_t)rl0 * ld + cs * 8, d + rl0 * 64 + cp * 8);
    GLOAD16(g0 + (size_t)rl1 * ld + cs * 8, d + rl1 * 64 + cp * 8);
  };
  // LDS layout (u16): buf b at b*32768: A half0 @0, A half1 @8192,
  //                                     B half0 @16384, B half1 @24576.
  // prologue issue order: A0(0),B0(0),B1(0),A1(0),B0(1),A0(1),B1(1)
  stage(A + (size_t)mBase * lda,          lda, lds + 0);
  stage(B + (size_t)nBase * ldb,          ldb, lds + 16384);
  stage(B + (size_t)(nBase + 128) * ldb,  ldb, lds + 24576);
  stage(A + (size_t)(mBase + 128) * lda,  lda, lds + 8192);
  stage(B + (size_t)nBase * ldb + 64,         ldb, lds + 32768 + 16384);
  stage(A + (size_t)mBase * lda + 64,         lda, lds + 32768);
  stage(B + (size_t)(nBase + 128) * ldb + 64, ldb, lds + 32768 + 24576);

  bf16x8 af[4][2], b0[2][2], b1[2][2];

  for (int tt = 0; tt < NT; ++tt) {
    const int cur = tt & 1;
    u16* bufA = lds + cur * 32768;
    u16* bufB = bufA + 16384;
    u16* bufN = lds + ((tt + 1) & 1) * 32768;   // buffer of tile t+1
    int t1 = tt + 1; if (t1 >= NT) t1 -= NT;    // wrap: garbage-but-valid
    int t2 = tt + 2; if (t2 >= NT) t2 -= NT;
    const int k1 = t1 * 64, k2 = t2 * 64;

    // ---------------- phase 1: (mh0, nh0) ----------------
    VMCNT10;
    SBAR;
    stage(A + (size_t)(mBase + 128) * lda + k1, lda, bufN + 8192);     // A1(t+1)
#pragma unroll
    for (int mi = 0; mi < 4; ++mi) {
      int row = wr * 64 + mi * 16 + lr16;                              // A half0
#pragma unroll
      for (int kk = 0; kk < 2; ++kk) {
        int p = (kk * 4 + hi) ^ (row & 7);
        af[mi][kk] = *(const bf16x8*)&bufA[row * 64 + p * 8];
      }
    }
#pragma unroll
    for (int ni = 0; ni < 2; ++ni) {
      int row = wc * 32 + ni * 16 + lr16;                              // B half0
#pragma unroll
      for (int kk = 0; kk < 2; ++kk) {
        int p = (kk * 4 + hi) ^ (row & 7);
        b0[ni][kk] = *(const bf16x8*)&bufB[row * 64 + p * 8];
      }
    }
    LGKM0;
    __builtin_amdgcn_s_setprio(1);
#pragma unroll
    for (int kk = 0; kk < 2; ++kk)
#pragma unroll
      for (int mi = 0; mi < 4; ++mi)
#pragma unroll
        for (int ni = 0; ni < 2; ++ni)
          acc[mi][ni] = __builtin_amdgcn_mfma_f32_16x16x32_bf16(af[mi][kk], b0[ni][kk], acc[mi][ni], 0, 0, 0);
    __builtin_amdgcn_s_setprio(0);

    // ---------------- phase 2: (mh0, nh1) ----------------
    VMCNT10;
    SBAR;
    stage(B + (size_t)nBase * ldb + k2, ldb, bufB);                    // B0(t+2)
#pragma unroll
    for (int ni = 0; ni < 2; ++ni) {
      int row = 128 + wc * 32 + ni * 16 + lr16;                        // B half1
#pragma unroll
      for (int kk = 0; kk < 2; ++kk) {
        int p = (kk * 4 + hi) ^ (row & 7);
        b1[ni][kk] = *(const bf16x8*)&bufB[row * 64 + p * 8];
      }
    }
    LGKM0;
    __builtin_amdgcn_s_setprio(1);
#pragma unroll
    for (int kk = 0; kk < 2; ++kk)
#pragma unroll
      for (int mi = 0; mi < 4; ++mi)
#pragma unroll
        for (int ni = 0; ni < 2; ++ni)
          acc[mi][2 + ni] = __builtin_amdgcn_mfma_f32_16x16x32_bf16(af[mi][kk], b1[ni][kk], acc[mi][2 + ni], 0, 0, 0);
    __builtin_amdgcn_s_setprio(0);

    // ---------------- phase 3: (mh1, nh1) ----------------
    VMCNT10;
    SBAR;
    stage(A + (size_t)mBase * lda + k2, lda, bufA);                    // A0(t+2)
#pragma unroll
    for (int mi = 0; mi < 4; ++mi) {
      int row = 128 + wr * 64 + mi * 16 + lr16;                        // A half1
#pragma unroll
      for (int kk = 0; kk < 2; ++kk) {
        int p = (kk * 4 + hi) ^ (row & 7);
        af[mi][kk] = *(const bf16x8*)&bufA[row * 64 + p * 8];
      }
    }
    LGKM0;
    __builtin_amdgcn_s_setprio(1);
#pragma unroll
    for (int kk = 0; kk < 2; ++kk)
#pragma unroll
      for (int mi = 0; mi < 4; ++mi)
#pragma unroll
        for (int ni = 0; ni < 2; ++ni)
          acc[4 + mi][2 + ni] = __builtin_amdgcn_mfma_f32_16x16x32_bf16(af[mi][kk], b1[ni][kk], acc[4 + mi][2 + ni], 0, 0, 0);
    __builtin_amdgcn_s_setprio(0);

    // ---------------- phase 4: (mh1, nh0) ----------------
    SBAR;
    stage(B + (size_t)(nBase + 128) * ldb + k2, ldb, bufB + 8192);     // B1(t+2)
    __builtin_amdgcn_s_setprio(1);
#pragma unroll
    for (int kk = 0; kk < 2; ++kk)
#pragma unroll
      for (int mi = 0; mi < 4; ++mi)
#pragma unroll
        for (int ni = 0; ni < 2; ++ni)
          acc[4 + mi][ni] = __builtin_amdgcn_mfma_f32_16x16x32_bf16(af[mi][kk], b0[ni][kk], acc[4 + mi][ni], 0, 0, 0);
    __builtin_amdgcn_s_setprio(0);
  }

  // epilogue
#pragma unroll
  for (int m = 0; m < 8; ++m) {
    int row0 = mBase + (m >> 2) * 128 + wr * 64 + (m & 3) * 16 + hi * 4;
#pragma unroll
    for (int n = 0; n < 4; ++n) {
      int col = nBase + (n >> 1) * 128 + wc * 32 + (n & 1) * 16 + lr16;
      f32x4 v = acc[m][n];
#pragma unroll
      for (int r = 0; r < 4; ++r) C[(size_t)(row0 + r) * ldc + col] = v[r];
    }
  }
}

// out_b = x_b @ P_b : A=xb (16384 rows), B=PT[batch], C=out f32. grid (4,64).
__global__ __launch_bounds__(512) void gemm256_out(const u16* __restrict__ xb,
                                                   const u16* __restrict__ PT,
                                                   float* __restrict__ out) {
  __shared__ u16 lds[65536];
  int bx, by, bz;
  xcd_swizzle(bx, by, bz);
  const u16* Bp = PT + (size_t)(by >> 4) * 1048576;
  gemm256_core(xb, Bp, out, 1024, 1024, 1024, 1024, by * 256, bx * 256, lds);
}

// Gram split-K partials: z=b*4+kc, Gp[z] = chunk self-NT. grid (4,4,16).
__global__ __launch_bounds__(512) void gemm256_gram(const u16* __restrict__ xT,
                                                    float* __restrict__ Gp) {
  __shared__ u16 lds[65536];
  int bx, by, bz;
  xcd_swizzle(bx, by, bz);
  const int b = bz >> 2, kc = bz & 3;
  const u16* Ap = xT + (size_t)b * 4096 + (size_t)kc * 1024;
  gemm256_core(Ap, Ap, Gp + (size_t)bz * 1048576, 16384, 16384, 1024, 1024,
               by * 256, bx * 256, lds);
}

// ---------- reduce 4 f32 partials -> bf16 G ----------
__global__ void reduce_gram(const float* __restrict__ Gp, u16* __restrict__ G) {
  const size_t MW = 1048576;
  int b = blockIdx.y;
  size_t i = ((size_t)blockIdx.x * 256 + threadIdx.x) * 4;
  const float* p = Gp + (size_t)b * 4 * MW + i;
  float4 s0 = *(const float4*)&p[0];
  float4 s1 = *(const float4*)&p[MW];
  float4 s2 = *(const float4*)&p[2 * MW];
  float4 s3 = *(const float4*)&p[3 * MW];
  u16 o[4];
  o[0] = f2bf(s0.x + s1.x + s2.x + s3.x);
  o[1] = f2bf(s0.y + s1.y + s2.y + s3.y);
  o[2] = f2bf(s0.z + s1.z + s2.z + s3.z);
  o[3] = f2bf(s0.w + s1.w + s2.w + s3.w);
  *(uint64_t*)&G[b * MW + i] = *(const uint64_t*)o;
}

// ---------------- host-side orchestration ----------------
// out_b = x_b @ W1 @ G_b @ W2 ; W1 = wq wk^T, W2 = wv wo, G_b = x_b^T x_b.
extern "C" void kernel_launch(void* const* d_in, const int* in_sizes, int n_in,
                              void* d_out, int out_size, void* d_ws, size_t ws_size,
                              hipStream_t stream) {
  const float* x  = (const float*)d_in[0];
  const float* wq = (const float*)d_in[1];
  const float* wk = (const float*)d_in[2];
  const float* wv = (const float*)d_in[3];
  const float* wo = (const float*)d_in[4];
  float* out = (float*)d_out;

  u16* ws = (u16*)d_ws;
  const size_t MW = 1048576;
  u16* xb  = ws;                    // [16384][1024]
  u16* xT  = ws + 16 * MW;          // [1024][16384]
  u16* WA  = ws + 32 * MW;          // [wq][woT]
  u16* WBb = ws + 34 * MW;          // [wk][wv]
  u16* W12 = ws + 36 * MW;          // [W1][W2T]
  u16* G   = ws + 38 * MW;          // [4][1024][1024]
  u16* S   = ws + 42 * MW;          // [4]
  u16* PT  = ws + 46 * MW;          // [4]
  float* Gp = (float*)(ws + 50 * MW);  // [16][1024][1024] f32 partials

  // casts
  cast_x_tr<<<dim3(16, 256), 256, 0, stream>>>(x, xb, xT);
  cast_w_plain<<<dim3(512, 1, 3), 256, 0, stream>>>(wq, wk, wv,
                                                    WA, WBb, WBb + MW);
  cast_trans<<<dim3(16, 16), 256, 0, stream>>>(wo, WA + MW);

  // merged small: W1 = NT(wq, wk), W2T = NT(woT, wv)
  gemm_bt<false><<<dim3(8, 8, 2), 256, 0, stream>>>(WA, WBb, W12,
                                                    1024, 1024, 1024, 1024,
                                                    MW, MW, MW);
  // Gram split-K on the 8-phase 256^2 kernel
  gemm256_gram<<<dim3(4, 4, 16), 512, 0, stream>>>(xT, Gp);
  reduce_gram<<<dim3(1024, 4), 256, 0, stream>>>(Gp, G);

  // S_b = NT(W2T, G_b)
  gemm_bt<false><<<dim3(8, 8, 4), 256, 0, stream>>>(W12 + MW, G, S,
                                                    1024, 1024, 1024, 1024,
                                                    0, MW, MW);
  // PT_b = NT(S_b, W1)
  gemm_bt<false><<<dim3(8, 8, 4), 256, 0, stream>>>(S, W12, PT,
                                                    1024, 1024, 1024, 1024,
                                                    MW, 0, MW);
  // out_b = x_b @ P_b on the 8-phase 256^2 kernel (f32 out)
  gemm256_out<<<dim3(4, 64), 512, 0, stream>>>(xb, PT, out);
}

// Round 6
// 178.564 us; speedup vs baseline: 4.0088x; 1.0861x over previous
//
#include <hip/hip_runtime.h>
#include <hip/hip_bf16.h>
#include <stdint.h>

typedef unsigned short u16;
typedef short bf16x8 __attribute__((ext_vector_type(8)));
typedef float f32x4 __attribute__((ext_vector_type(4)));

#define GLOAD16(gp, lp) __builtin_amdgcn_global_load_lds( \
    (const __attribute__((address_space(1))) uint32_t*)(gp), \
    (__attribute__((address_space(3))) uint32_t*)(lp), 16, 0, 0)

#define VMCNT10 do { asm volatile("s_waitcnt vmcnt(10)" ::: "memory"); \
                     __builtin_amdgcn_sched_barrier(0); } while (0)
#define SBAR    do { __builtin_amdgcn_s_barrier(); \
                     __builtin_amdgcn_sched_barrier(0); } while (0)
#define LGKM0   do { asm volatile("s_waitcnt lgkmcnt(0)" ::: "memory"); \
                     __builtin_amdgcn_sched_barrier(0); } while (0)

__device__ __forceinline__ u16 f2bf(float f) {
  union { float f; uint32_t u; } x; x.f = f;
  return (u16)((x.u + 0x7FFFu + ((x.u >> 16) & 1u)) >> 16);
}
__device__ __forceinline__ float bf2f(u16 h) {
  union { uint32_t u; float f; } x; x.u = (uint32_t)h << 16;
  return x.f;
}

// Bijective XCD-chunked block swizzle (T1, m204 form). Requires nwg % 8 == 0.
__device__ __forceinline__ void xcd_swizzle(int& bx, int& by, int& bz) {
  const int gx = gridDim.x, gy = gridDim.y;
  const int nwg = gx * gy * (int)gridDim.z;
  const int lin = ((int)blockIdx.z * gy + (int)blockIdx.y) * gx + (int)blockIdx.x;
  const int q = nwg >> 3;
  const int wl = (lin & 7) * q + (lin >> 3);
  bz = wl / (gx * gy);
  const int rem = wl - bz * gx * gy;
  by = rem / gx;
  bx = rem - by * gx;
}

// ------- cast x: xb[t][d] bf16 (plain) AND xT[d][t] bf16 (transposed) -------
__global__ __launch_bounds__(256) void cast_x_tr(const float* __restrict__ x,
                                                 u16* __restrict__ xb,
                                                 u16* __restrict__ xT) {
  __shared__ float tile[64][65];
  const int t = threadIdx.x;
  const int lr = t >> 2, lc = (t & 3) * 16;
  const int d0 = blockIdx.x * 64;
  const int t0 = blockIdx.y * 64;
  const float* src = x + (size_t)(t0 + lr) * 1024 + d0 + lc;
  u16 pl[16];
#pragma unroll
  for (int j = 0; j < 4; ++j) {
    float4 v = *(const float4*)&src[j * 4];
    tile[lr][lc + j * 4 + 0] = v.x;
    tile[lr][lc + j * 4 + 1] = v.y;
    tile[lr][lc + j * 4 + 2] = v.z;
    tile[lr][lc + j * 4 + 3] = v.w;
    pl[j * 4 + 0] = f2bf(v.x); pl[j * 4 + 1] = f2bf(v.y);
    pl[j * 4 + 2] = f2bf(v.z); pl[j * 4 + 3] = f2bf(v.w);
  }
  u16* pdst = xb + (size_t)(t0 + lr) * 1024 + d0 + lc;
  *(uint4*)&pdst[0] = *(const uint4*)&pl[0];
  *(uint4*)&pdst[8] = *(const uint4*)&pl[8];
  __syncthreads();
  u16 tr[16];
#pragma unroll
  for (int j = 0; j < 16; ++j) tr[j] = f2bf(tile[lc + j][lr]);
  u16* tdst = xT + (size_t)(d0 + lr) * 16384 + t0 + lc;
  *(uint4*)&tdst[0] = *(const uint4*)&tr[0];
  *(uint4*)&tdst[8] = *(const uint4*)&tr[8];
}

// ------- unified weight cast: z=0..2 plain (wq,wk,wv), z=3 transpose (wo) -------
__global__ __launch_bounds__(256) void cast_weights(const float* __restrict__ wq,
                                                    const float* __restrict__ wk,
                                                    const float* __restrict__ wv,
                                                    const float* __restrict__ wo,
                                                    u16* __restrict__ WA,
                                                    u16* __restrict__ WBb) {
  __shared__ float tile[64][65];
  const int z = blockIdx.z;
  const float* in = z == 0 ? wq : z == 1 ? wk : z == 2 ? wv : wo;
  u16* o = z == 0 ? WA : z == 1 ? WBb : z == 2 ? WBb + 1048576 : WA + 1048576;
  const int t = threadIdx.x;
  const int lr = t >> 2, lc = (t & 3) * 16;
  const int r0 = blockIdx.y * 64, c0 = blockIdx.x * 64;
  const float* src = in + (size_t)(r0 + lr) * 1024 + c0 + lc;
  if (z < 3) {
    u16 p[16];
#pragma unroll
    for (int j = 0; j < 4; ++j) {
      float4 v = *(const float4*)&src[j * 4];
      p[j * 4 + 0] = f2bf(v.x); p[j * 4 + 1] = f2bf(v.y);
      p[j * 4 + 2] = f2bf(v.z); p[j * 4 + 3] = f2bf(v.w);
    }
    u16* dst = o + (size_t)(r0 + lr) * 1024 + c0 + lc;
    *(uint4*)&dst[0] = *(const uint4*)&p[0];
    *(uint4*)&dst[8] = *(const uint4*)&p[8];
  } else {
#pragma unroll
    for (int j = 0; j < 4; ++j) {
      float4 v = *(const float4*)&src[j * 4];
      tile[lr][lc + j * 4 + 0] = v.x;
      tile[lr][lc + j * 4 + 1] = v.y;
      tile[lr][lc + j * 4 + 2] = v.z;
      tile[lr][lc + j * 4 + 3] = v.w;
    }
    __syncthreads();
    u16 tr[16];
#pragma unroll
    for (int j = 0; j < 16; ++j) tr[j] = f2bf(tile[lc + j][lr]);
    u16* dst = o + (size_t)(c0 + lr) * 1024 + r0 + lc;
    *(uint4*)&dst[0] = *(const uint4*)&tr[0];
    *(uint4*)&dst[8] = *(const uint4*)&tr[8];
  }
}

// ---------------- 128^2 batched NT GEMM (small matrices) --------
template <bool F32OUT>
__global__ __launch_bounds__(256) void gemm_bt(const u16* __restrict__ A,
                                               const u16* __restrict__ B,
                                               void* __restrict__ C,
                                               int lda, int ldb, int ldc, int K,
                                               size_t sA, size_t sB, size_t sC) {
  __shared__ u16 lds[2 * 8192];
  int bx, by, bz;
  xcd_swizzle(bx, by, bz);
  A += (size_t)bz * sA;
  B += (size_t)bz * sB;
  const int t = threadIdx.x;
  const int l = t & 63;
  const int w = t >> 6;
  const int wr = w >> 1, wc = w & 1;
  const int lr16 = l & 15, hi = l >> 4;
  const int mBase = by * 128;
  const int nBase = bx * 128;

  f32x4 acc[4][4];
#pragma unroll
  for (int m = 0; m < 4; ++m)
#pragma unroll
    for (int n = 0; n < 4; ++n) acc[m][n] = (f32x4){0.f, 0.f, 0.f, 0.f};

  for (int kt = 0; kt < K; kt += 64) {
    __syncthreads();
#pragma unroll
    for (int i = 0; i < 4; ++i) {
      int s = i * 256 + t;
      int row = s >> 3, cp = s & 7;
      int clog = cp ^ (row & 7);
      const u16* g = A + (size_t)(mBase + row) * lda + kt + clog * 8;
      GLOAD16(g, &lds[s * 8]);
    }
#pragma unroll
    for (int i = 0; i < 4; ++i) {
      int s = i * 256 + t;
      int row = s >> 3, cp = s & 7;
      int clog = cp ^ (row & 7);
      const u16* g = B + (size_t)(nBase + row) * ldb + kt + clog * 8;
      GLOAD16(g, &lds[8192 + s * 8]);
    }
    asm volatile("s_waitcnt vmcnt(0)" ::: "memory");
    __syncthreads();
#pragma unroll
    for (int ks = 0; ks < 2; ++ks) {
      bf16x8 af[4], bfr[4];
#pragma unroll
      for (int m = 0; m < 4; ++m) {
        int row = wr * 64 + m * 16 + lr16;
        int p = (ks * 4 + hi) ^ (row & 7);
        af[m] = *(const bf16x8*)&lds[row * 64 + p * 8];
      }
#pragma unroll
      for (int n = 0; n < 4; ++n) {
        int row = wc * 64 + n * 16 + lr16;
        int p = (ks * 4 + hi) ^ (row & 7);
        bfr[n] = *(const bf16x8*)&lds[8192 + row * 64 + p * 8];
      }
#pragma unroll
      for (int m = 0; m < 4; ++m)
#pragma unroll
        for (int n = 0; n < 4; ++n)
          acc[m][n] = __builtin_amdgcn_mfma_f32_16x16x32_bf16(af[m], bfr[n], acc[m][n], 0, 0, 0);
    }
  }

#pragma unroll
  for (int m = 0; m < 4; ++m) {
    int row0 = mBase + wr * 64 + m * 16 + hi * 4;
#pragma unroll
    for (int n = 0; n < 4; ++n) {
      int col = nBase + wc * 64 + n * 16 + lr16;
      f32x4 v = acc[m][n];
      if (F32OUT) {
        float* Cf = (float*)C + (size_t)bz * sC;
#pragma unroll
        for (int r = 0; r < 4; ++r) Cf[(size_t)(row0 + r) * ldc + col] = v[r];
      } else {
        u16* Cb = (u16*)C + (size_t)bz * sC;
#pragma unroll
        for (int r = 0; r < 4; ++r) Cb[(size_t)(row0 + r) * ldc + col] = f2bf(v[r]);
      }
    }
  }
}

// =================== 256^2 8-phase NT GEMM core ===================
// BM=BN=256, BK=64, 512 thr (8 waves 2Mx4N). LDS: 2 buf x (A 256x64 | B 256x64).
// Frag rows: A(m)=(m>>2)*128+wr*64+(m&3)*16 ; B(n)=(n>>1)*128+wc*32+(n&1)*16
// -> each phase reads exactly one contiguous 128-row half of A or B.
// Stage schedule (one half/phase): p1->A1(t+1), p2->B0(t+2), p3->A0(t+2),
// p4->B1(t+2); steady-state counted wait = vmcnt(10) at p1..p3.
template <bool F32OUT>
__device__ __forceinline__ void gemm256_core(const u16* __restrict__ A,
                                             const u16* __restrict__ B,
                                             void* __restrict__ C,
                                             int lda, int ldb, int ldc, int K,
                                             int mBase, int nBase, u16* lds) {
  const int t = threadIdx.x;
  const int l = t & 63;
  const int wid = t >> 6;
  const int wr = wid >> 2;          // 0..1
  const int wc = wid & 3;           // 0..3
  const int lr16 = l & 15, hi = l >> 4;
  const int rl0 = t >> 3;           // rows 0..63   (g=0)
  const int rl1 = rl0 + 64;         // rows 64..127 (g=1)
  const int cp  = t & 7;
  const int cs  = cp ^ (rl0 & 7);   // pre-swizzled source chunk
  const int NT = K >> 6;

  f32x4 acc[8][4];
#pragma unroll
  for (int m = 0; m < 8; ++m)
#pragma unroll
    for (int n = 0; n < 4; ++n) acc[m][n] = (f32x4){0.f, 0.f, 0.f, 0.f};

  auto stage = [&](const u16* g0, int ld, u16* d) {
    GLOAD16(g0 + (size_t)rl0 * ld + cs * 8, d + rl0 * 64 + cp * 8);
    GLOAD16(g0 + (size_t)rl1 * ld + cs * 8, d + rl1 * 64 + cp * 8);
  };
  // LDS layout (u16): buf b at b*32768: A half0 @0, A half1 @8192,
  //                                     B half0 @16384, B half1 @24576.
  stage(A + (size_t)mBase * lda,          lda, lds + 0);
  stage(B + (size_t)nBase * ldb,          ldb, lds + 16384);
  stage(B + (size_t)(nBase + 128) * ldb,  ldb, lds + 24576);
  stage(A + (size_t)(mBase + 128) * lda,  lda, lds + 8192);
  stage(B + (size_t)nBase * ldb + 64,         ldb, lds + 32768 + 16384);
  stage(A + (size_t)mBase * lda + 64,         lda, lds + 32768);
  stage(B + (size_t)(nBase + 128) * ldb + 64, ldb, lds + 32768 + 24576);

  bf16x8 af[4][2], b0[2][2], b1[2][2];

  for (int tt = 0; tt < NT; ++tt) {
    const int cur = tt & 1;
    u16* bufA = lds + cur * 32768;
    u16* bufB = bufA + 16384;
    u16* bufN = lds + ((tt + 1) & 1) * 32768;
    int t1 = tt + 1; if (t1 >= NT) t1 -= NT;    // wrap: garbage-but-valid
    int t2 = tt + 2; if (t2 >= NT) t2 -= NT;
    const int k1 = t1 * 64, k2 = t2 * 64;

    // ---------------- phase 1: (mh0, nh0) ----------------
    VMCNT10;
    SBAR;
    stage(A + (size_t)(mBase + 128) * lda + k1, lda, bufN + 8192);     // A1(t+1)
#pragma unroll
    for (int mi = 0; mi < 4; ++mi) {
      int row = wr * 64 + mi * 16 + lr16;                              // A half0
#pragma unroll
      for (int kk = 0; kk < 2; ++kk) {
        int p = (kk * 4 + hi) ^ (row & 7);
        af[mi][kk] = *(const bf16x8*)&bufA[row * 64 + p * 8];
      }
    }
#pragma unroll
    for (int ni = 0; ni < 2; ++ni) {
      int row = wc * 32 + ni * 16 + lr16;                              // B half0
#pragma unroll
      for (int kk = 0; kk < 2; ++kk) {
        int p = (kk * 4 + hi) ^ (row & 7);
        b0[ni][kk] = *(const bf16x8*)&bufB[row * 64 + p * 8];
      }
    }
    LGKM0;
    __builtin_amdgcn_s_setprio(1);
#pragma unroll
    for (int kk = 0; kk < 2; ++kk)
#pragma unroll
      for (int mi = 0; mi < 4; ++mi)
#pragma unroll
        for (int ni = 0; ni < 2; ++ni)
          acc[mi][ni] = __builtin_amdgcn_mfma_f32_16x16x32_bf16(af[mi][kk], b0[ni][kk], acc[mi][ni], 0, 0, 0);
    __builtin_amdgcn_s_setprio(0);

    // ---------------- phase 2: (mh0, nh1) ----------------
    VMCNT10;
    SBAR;
    stage(B + (size_t)nBase * ldb + k2, ldb, bufB);                    // B0(t+2)
#pragma unroll
    for (int ni = 0; ni < 2; ++ni) {
      int row = 128 + wc * 32 + ni * 16 + lr16;                        // B half1
#pragma unroll
      for (int kk = 0; kk < 2; ++kk) {
        int p = (kk * 4 + hi) ^ (row & 7);
        b1[ni][kk] = *(const bf16x8*)&bufB[row * 64 + p * 8];
      }
    }
    LGKM0;
    __builtin_amdgcn_s_setprio(1);
#pragma unroll
    for (int kk = 0; kk < 2; ++kk)
#pragma unroll
      for (int mi = 0; mi < 4; ++mi)
#pragma unroll
        for (int ni = 0; ni < 2; ++ni)
          acc[mi][2 + ni] = __builtin_amdgcn_mfma_f32_16x16x32_bf16(af[mi][kk], b1[ni][kk], acc[mi][2 + ni], 0, 0, 0);
    __builtin_amdgcn_s_setprio(0);

    // ---------------- phase 3: (mh1, nh1) ----------------
    VMCNT10;
    SBAR;
    stage(A + (size_t)mBase * lda + k2, lda, bufA);                    // A0(t+2)
#pragma unroll
    for (int mi = 0; mi < 4; ++mi) {
      int row = 128 + wr * 64 + mi * 16 + lr16;                        // A half1
#pragma unroll
      for (int kk = 0; kk < 2; ++kk) {
        int p = (kk * 4 + hi) ^ (row & 7);
        af[mi][kk] = *(const bf16x8*)&bufA[row * 64 + p * 8];
      }
    }
    LGKM0;
    __builtin_amdgcn_s_setprio(1);
#pragma unroll
    for (int kk = 0; kk < 2; ++kk)
#pragma unroll
      for (int mi = 0; mi < 4; ++mi)
#pragma unroll
        for (int ni = 0; ni < 2; ++ni)
          acc[4 + mi][2 + ni] = __builtin_amdgcn_mfma_f32_16x16x32_bf16(af[mi][kk], b1[ni][kk], acc[4 + mi][2 + ni], 0, 0, 0);
    __builtin_amdgcn_s_setprio(0);

    // ---------------- phase 4: (mh1, nh0) ----------------
    SBAR;
    stage(B + (size_t)(nBase + 128) * ldb + k2, ldb, bufB + 8192);     // B1(t+2)
    __builtin_amdgcn_s_setprio(1);
#pragma unroll
    for (int kk = 0; kk < 2; ++kk)
#pragma unroll
      for (int mi = 0; mi < 4; ++mi)
#pragma unroll
        for (int ni = 0; ni < 2; ++ni)
          acc[4 + mi][ni] = __builtin_amdgcn_mfma_f32_16x16x32_bf16(af[mi][kk], b0[ni][kk], acc[4 + mi][ni], 0, 0, 0);
    __builtin_amdgcn_s_setprio(0);
  }

  // epilogue
#pragma unroll
  for (int m = 0; m < 8; ++m) {
    int row0 = mBase + (m >> 2) * 128 + wr * 64 + (m & 3) * 16 + hi * 4;
#pragma unroll
    for (int n = 0; n < 4; ++n) {
      int col = nBase + (n >> 1) * 128 + wc * 32 + (n & 1) * 16 + lr16;
      f32x4 v = acc[m][n];
      if (F32OUT) {
        float* Cf = (float*)C;
#pragma unroll
        for (int r = 0; r < 4; ++r) Cf[(size_t)(row0 + r) * ldc + col] = v[r];
      } else {
        u16* Cb = (u16*)C;
#pragma unroll
        for (int r = 0; r < 4; ++r) Cb[(size_t)(row0 + r) * ldc + col] = f2bf(v[r]);
      }
    }
  }
}

// out_b = x_b @ P_b : A=xb (16384 rows), B=PT[batch], C=out f32. grid (4,64).
__global__ __launch_bounds__(512) void gemm256_out(const u16* __restrict__ xb,
                                                   const u16* __restrict__ PT,
                                                   float* __restrict__ out) {
  __shared__ u16 lds[65536];
  int bx, by, bz;
  xcd_swizzle(bx, by, bz);
  const u16* Bp = PT + (size_t)(by >> 4) * 1048576;
  gemm256_core<true>(xb, Bp, out, 1024, 1024, 1024, 1024, by * 256, bx * 256, lds);
}

// Gram split-K partials (bf16): z=b*4+kc. grid (4,4,16).
__global__ __launch_bounds__(512) void gemm256_gram(const u16* __restrict__ xT,
                                                    u16* __restrict__ Gp) {
  __shared__ u16 lds[65536];
  int bx, by, bz;
  xcd_swizzle(bx, by, bz);
  const int b = bz >> 2, kc = bz & 3;
  const u16* Ap = xT + (size_t)b * 4096 + (size_t)kc * 1024;
  gemm256_core<false>(Ap, Ap, Gp + (size_t)bz * 1048576, 16384, 16384, 1024, 1024,
                      by * 256, bx * 256, lds);
}

// ---------- reduce 4 bf16 partials -> bf16 G ----------
__global__ void reduce_gram(const u16* __restrict__ Gp, u16* __restrict__ G) {
  const size_t MW = 1048576;
  int b = blockIdx.y;
  size_t i = ((size_t)blockIdx.x * 256 + threadIdx.x) * 8;
  const u16* p = Gp + (size_t)b * 4 * MW + i;
  u16 a0[8], a1[8], a2[8], a3[8], o[8];
  *(uint4*)a0 = *(const uint4*)&p[0];
  *(uint4*)a1 = *(const uint4*)&p[MW];
  *(uint4*)a2 = *(const uint4*)&p[2 * MW];
  *(uint4*)a3 = *(const uint4*)&p[3 * MW];
#pragma unroll
  for (int j = 0; j < 8; ++j)
    o[j] = f2bf(bf2f(a0[j]) + bf2f(a1[j]) + bf2f(a2[j]) + bf2f(a3[j]));
  *(uint4*)&G[b * MW + i] = *(const uint4*)o;
}

// ---------------- host-side orchestration ----------------
// out_b = x_b @ W1 @ G_b @ W2 ; W1 = wq wk^T, W2 = wv wo, G_b = x_b^T x_b.
extern "C" void kernel_launch(void* const* d_in, const int* in_sizes, int n_in,
                              void* d_out, int out_size, void* d_ws, size_t ws_size,
                              hipStream_t stream) {
  const float* x  = (const float*)d_in[0];
  const float* wq = (const float*)d_in[1];
  const float* wk = (const float*)d_in[2];
  const float* wv = (const float*)d_in[3];
  const float* wo = (const float*)d_in[4];
  float* out = (float*)d_out;

  u16* ws = (u16*)d_ws;
  const size_t MW = 1048576;
  u16* xb  = ws;                    // [16384][1024]
  u16* xT  = ws + 16 * MW;          // [1024][16384]
  u16* WA  = ws + 32 * MW;          // [wq][woT]
  u16* WBb = ws + 34 * MW;          // [wk][wv]
  u16* W12 = ws + 36 * MW;          // [W1][W2T]
  u16* G   = ws + 38 * MW;          // [4][1024][1024]
  u16* S   = ws + 42 * MW;          // [4]
  u16* PT  = ws + 46 * MW;          // [4]
  u16* Gp  = ws + 50 * MW;          // [16][1024][1024] bf16 partials (32 MB)

  // casts (2 launches)
  cast_x_tr<<<dim3(16, 256), 256, 0, stream>>>(x, xb, xT);
  cast_weights<<<dim3(16, 16, 4), 256, 0, stream>>>(wq, wk, wv, wo, WA, WBb);

  // merged small: W1 = NT(wq, wk), W2T = NT(woT, wv)
  gemm_bt<false><<<dim3(8, 8, 2), 256, 0, stream>>>(WA, WBb, W12,
                                                    1024, 1024, 1024, 1024,
                                                    MW, MW, MW);
  // Gram split-K on the 8-phase 256^2 kernel (bf16 partials)
  gemm256_gram<<<dim3(4, 4, 16), 512, 0, stream>>>(xT, Gp);
  reduce_gram<<<dim3(512, 4), 256, 0, stream>>>(Gp, G);

  // S_b = NT(W2T, G_b)
  gemm_bt<false><<<dim3(8, 8, 4), 256, 0, stream>>>(W12 + MW, G, S,
                                                    1024, 1024, 1024, 1024,
                                                    0, MW, MW);
  // PT_b = NT(S_b, W1)
  gemm_bt<false><<<dim3(8, 8, 4), 256, 0, stream>>>(S, W12, PT,
                                                    1024, 1024, 1024, 1024,
                                                    MW, 0, MW);
  // out_b = x_b @ P_b on the 8-phase 256^2 kernel (f32 out)
  gemm256_out<<<dim3(4, 64), 512, 0, stream>>>(xb, PT, out);
}

// Round 7
// 170.802 us; speedup vs baseline: 4.1910x; 1.0454x over previous
//
#include <hip/hip_runtime.h>
#include <hip/hip_bf16.h>
#include <stdint.h>

typedef unsigned short u16;
typedef short bf16x8 __attribute__((ext_vector_type(8)));
typedef float f32x4 __attribute__((ext_vector_type(4)));

#define GLOAD16(gp, lp) __builtin_amdgcn_global_load_lds( \
    (const __attribute__((address_space(1))) uint32_t*)(gp), \
    (__attribute__((address_space(3))) uint32_t*)(lp), 16, 0, 0)

#define VMCNT10 do { asm volatile("s_waitcnt vmcnt(10)" ::: "memory"); \
                     __builtin_amdgcn_sched_barrier(0); } while (0)
#define SBAR    do { __builtin_amdgcn_s_barrier(); \
                     __builtin_amdgcn_sched_barrier(0); } while (0)
#define LGKM0   do { asm volatile("s_waitcnt lgkmcnt(0)" ::: "memory"); \
                     __builtin_amdgcn_sched_barrier(0); } while (0)

__device__ __forceinline__ u16 f2bf(float f) {
  union { float f; uint32_t u; } x; x.f = f;
  return (u16)((x.u + 0x7FFFu + ((x.u >> 16) & 1u)) >> 16);
}
__device__ __forceinline__ float bf2f(u16 h) {
  union { uint32_t u; float f; } x; x.u = (uint32_t)h << 16;
  return x.f;
}

// Bijective XCD-chunked block swizzle (T1, m204 form). Requires nwg % 8 == 0.
__device__ __forceinline__ void xcd_swizzle(int& bx, int& by, int& bz) {
  const int gx = gridDim.x, gy = gridDim.y;
  const int nwg = gx * gy * (int)gridDim.z;
  const int lin = ((int)blockIdx.z * gy + (int)blockIdx.y) * gx + (int)blockIdx.x;
  const int q = nwg >> 3;
  const int wl = (lin & 7) * q + (lin >> 3);
  bz = wl / (gx * gy);
  const int rem = wl - bz * gx * gy;
  by = rem / gx;
  bx = rem - by * gx;
}

// ------- cast x: xb[t][d] bf16 (plain) AND xT[d][t] bf16 (transposed) -------
__global__ __launch_bounds__(256) void cast_x_tr(const float* __restrict__ x,
                                                 u16* __restrict__ xb,
                                                 u16* __restrict__ xT) {
  __shared__ float tile[64][65];
  const int t = threadIdx.x;
  const int lr = t >> 2, lc = (t & 3) * 16;
  const int d0 = blockIdx.x * 64;
  const int t0 = blockIdx.y * 64;
  const float* src = x + (size_t)(t0 + lr) * 1024 + d0 + lc;
  u16 pl[16];
#pragma unroll
  for (int j = 0; j < 4; ++j) {
    float4 v = *(const float4*)&src[j * 4];
    tile[lr][lc + j * 4 + 0] = v.x;
    tile[lr][lc + j * 4 + 1] = v.y;
    tile[lr][lc + j * 4 + 2] = v.z;
    tile[lr][lc + j * 4 + 3] = v.w;
    pl[j * 4 + 0] = f2bf(v.x); pl[j * 4 + 1] = f2bf(v.y);
    pl[j * 4 + 2] = f2bf(v.z); pl[j * 4 + 3] = f2bf(v.w);
  }
  u16* pdst = xb + (size_t)(t0 + lr) * 1024 + d0 + lc;
  *(uint4*)&pdst[0] = *(const uint4*)&pl[0];
  *(uint4*)&pdst[8] = *(const uint4*)&pl[8];
  __syncthreads();
  u16 tr[16];
#pragma unroll
  for (int j = 0; j < 16; ++j) tr[j] = f2bf(tile[lc + j][lr]);
  u16* tdst = xT + (size_t)(d0 + lr) * 16384 + t0 + lc;
  *(uint4*)&tdst[0] = *(const uint4*)&tr[0];
  *(uint4*)&tdst[8] = *(const uint4*)&tr[8];
}

// ------- unified weight cast: z=0..2 plain (wq,wk,wv), z=3 transpose (wo) -------
__global__ __launch_bounds__(256) void cast_weights(const float* __restrict__ wq,
                                                    const float* __restrict__ wk,
                                                    const float* __restrict__ wv,
                                                    const float* __restrict__ wo,
                                                    u16* __restrict__ WA,
                                                    u16* __restrict__ WBb) {
  __shared__ float tile[64][65];
  const int z = blockIdx.z;
  const float* in = z == 0 ? wq : z == 1 ? wk : z == 2 ? wv : wo;
  u16* o = z == 0 ? WA : z == 1 ? WBb : z == 2 ? WBb + 1048576 : WA + 1048576;
  const int t = threadIdx.x;
  const int lr = t >> 2, lc = (t & 3) * 16;
  const int r0 = blockIdx.y * 64, c0 = blockIdx.x * 64;
  const float* src = in + (size_t)(r0 + lr) * 1024 + c0 + lc;
  if (z < 3) {
    u16 p[16];
#pragma unroll
    for (int j = 0; j < 4; ++j) {
      float4 v = *(const float4*)&src[j * 4];
      p[j * 4 + 0] = f2bf(v.x); p[j * 4 + 1] = f2bf(v.y);
      p[j * 4 + 2] = f2bf(v.z); p[j * 4 + 3] = f2bf(v.w);
    }
    u16* dst = o + (size_t)(r0 + lr) * 1024 + c0 + lc;
    *(uint4*)&dst[0] = *(const uint4*)&p[0];
    *(uint4*)&dst[8] = *(const uint4*)&p[8];
  } else {
#pragma unroll
    for (int j = 0; j < 4; ++j) {
      float4 v = *(const float4*)&src[j * 4];
      tile[lr][lc + j * 4 + 0] = v.x;
      tile[lr][lc + j * 4 + 1] = v.y;
      tile[lr][lc + j * 4 + 2] = v.z;
      tile[lr][lc + j * 4 + 3] = v.w;
    }
    __syncthreads();
    u16 tr[16];
#pragma unroll
    for (int j = 0; j < 16; ++j) tr[j] = f2bf(tile[lc + j][lr]);
    u16* dst = o + (size_t)(c0 + lr) * 1024 + r0 + lc;
    *(uint4*)&dst[0] = *(const uint4*)&tr[0];
    *(uint4*)&dst[8] = *(const uint4*)&tr[8];
  }
}

// ------- 8-wave 128^2 batched NT GEMM (small matrices, occupancy-optimized) ----
// 512 thr = 8 waves (2M x 4N); wave owns 64x32 (acc 4x2). LDS 32 KB -> 2-3
// blocks/CU resident; cross-block overlap hides the per-K-step barrier drain.
__global__ __launch_bounds__(512) void gemm_bt8(const u16* __restrict__ A,
                                                const u16* __restrict__ B,
                                                u16* __restrict__ C,
                                                int lda, int ldb, int ldc, int K,
                                                size_t sA, size_t sB, size_t sC) {
  __shared__ u16 lds[2 * 8192];
  int bx, by, bz;
  xcd_swizzle(bx, by, bz);
  A += (size_t)bz * sA;
  B += (size_t)bz * sB;
  const int t = threadIdx.x;           // 0..511
  const int l = t & 63;
  const int wid = t >> 6;              // 0..7
  const int wr = wid >> 2, wc = wid & 3;
  const int lr16 = l & 15, hi = l >> 4;
  const int mBase = by * 128;
  const int nBase = bx * 128;

  f32x4 acc[4][2];
#pragma unroll
  for (int m = 0; m < 4; ++m)
#pragma unroll
    for (int n = 0; n < 2; ++n) acc[m][n] = (f32x4){0.f, 0.f, 0.f, 0.f};

  for (int kt = 0; kt < K; kt += 64) {
    __syncthreads();
#pragma unroll
    for (int i = 0; i < 2; ++i) {
      int s = i * 512 + t;
      int row = s >> 3, cp = s & 7;
      int clog = cp ^ (row & 7);
      GLOAD16(A + (size_t)(mBase + row) * lda + kt + clog * 8, &lds[s * 8]);
    }
#pragma unroll
    for (int i = 0; i < 2; ++i) {
      int s = i * 512 + t;
      int row = s >> 3, cp = s & 7;
      int clog = cp ^ (row & 7);
      GLOAD16(B + (size_t)(nBase + row) * ldb + kt + clog * 8, &lds[8192 + s * 8]);
    }
    asm volatile("s_waitcnt vmcnt(0)" ::: "memory");
    __syncthreads();
#pragma unroll
    for (int ks = 0; ks < 2; ++ks) {
      bf16x8 af[4], bfr[2];
#pragma unroll
      for (int m = 0; m < 4; ++m) {
        int row = wr * 64 + m * 16 + lr16;
        int p = (ks * 4 + hi) ^ (row & 7);
        af[m] = *(const bf16x8*)&lds[row * 64 + p * 8];
      }
#pragma unroll
      for (int n = 0; n < 2; ++n) {
        int row = wc * 32 + n * 16 + lr16;
        int p = (ks * 4 + hi) ^ (row & 7);
        bfr[n] = *(const bf16x8*)&lds[8192 + row * 64 + p * 8];
      }
#pragma unroll
      for (int m = 0; m < 4; ++m)
#pragma unroll
        for (int n = 0; n < 2; ++n)
          acc[m][n] = __builtin_amdgcn_mfma_f32_16x16x32_bf16(af[m], bfr[n], acc[m][n], 0, 0, 0);
    }
  }

#pragma unroll
  for (int m = 0; m < 4; ++m) {
    int row0 = mBase + wr * 64 + m * 16 + hi * 4;
#pragma unroll
    for (int n = 0; n < 2; ++n) {
      int col = nBase + wc * 32 + n * 16 + lr16;
      f32x4 v = acc[m][n];
      u16* Cb = C + (size_t)bz * sC;
#pragma unroll
      for (int r = 0; r < 4; ++r) Cb[(size_t)(row0 + r) * ldc + col] = f2bf(v[r]);
    }
  }
}

// =================== 256^2 8-phase NT GEMM core ===================
// BM=BN=256, BK=64, 512 thr (8 waves 2Mx4N). LDS: 2 buf x (A 256x64 | B 256x64).
// Frag rows: A(m)=(m>>2)*128+wr*64+(m&3)*16 ; B(n)=(n>>1)*128+wc*32+(n&1)*16
// -> each phase reads exactly one contiguous 128-row half of A or B.
// Stage schedule (one half/phase): p1->A1(t+1), p2->B0(t+2), p3->A0(t+2),
// p4->B1(t+2); steady-state counted wait = vmcnt(10) at p1..p3.
template <bool F32OUT>
__device__ __forceinline__ void gemm256_core(const u16* __restrict__ A,
                                             const u16* __restrict__ B,
                                             void* __restrict__ C,
                                             int lda, int ldb, int ldc, int K,
                                             int mBase, int nBase, u16* lds) {
  const int t = threadIdx.x;
  const int l = t & 63;
  const int wid = t >> 6;
  const int wr = wid >> 2;          // 0..1
  const int wc = wid & 3;           // 0..3
  const int lr16 = l & 15, hi = l >> 4;
  const int rl0 = t >> 3;           // rows 0..63   (g=0)
  const int rl1 = rl0 + 64;         // rows 64..127 (g=1)
  const int cp  = t & 7;
  const int cs  = cp ^ (rl0 & 7);   // pre-swizzled source chunk
  const int NT = K >> 6;

  f32x4 acc[8][4];
#pragma unroll
  for (int m = 0; m < 8; ++m)
#pragma unroll
    for (int n = 0; n < 4; ++n) acc[m][n] = (f32x4){0.f, 0.f, 0.f, 0.f};

  auto stage = [&](const u16* g0, int ld, u16* d) {
    GLOAD16(g0 + (size_t)rl0 * ld + cs * 8, d + rl0 * 64 + cp * 8);
    GLOAD16(g0 + (size_t)rl1 * ld + cs * 8, d + rl1 * 64 + cp * 8);
  };
  // LDS layout (u16): buf b at b*32768: A half0 @0, A half1 @8192,
  //                                     B half0 @16384, B half1 @24576.
  stage(A + (size_t)mBase * lda,          lda, lds + 0);
  stage(B + (size_t)nBase * ldb,          ldb, lds + 16384);
  stage(B + (size_t)(nBase + 128) * ldb,  ldb, lds + 24576);
  stage(A + (size_t)(mBase + 128) * lda,  lda, lds + 8192);
  stage(B + (size_t)nBase * ldb + 64,         ldb, lds + 32768 + 16384);
  stage(A + (size_t)mBase * lda + 64,         lda, lds + 32768);
  stage(B + (size_t)(nBase + 128) * ldb + 64, ldb, lds + 32768 + 24576);

  bf16x8 af[4][2], b0[2][2], b1[2][2];

  for (int tt = 0; tt < NT; ++tt) {
    const int cur = tt & 1;
    u16* bufA = lds + cur * 32768;
    u16* bufB = bufA + 16384;
    u16* bufN = lds + ((tt + 1) & 1) * 32768;
    int t1 = tt + 1; if (t1 >= NT) t1 -= NT;    // wrap: garbage-but-valid
    int t2 = tt + 2; if (t2 >= NT) t2 -= NT;
    const int k1 = t1 * 64, k2 = t2 * 64;

    // ---------------- phase 1: (mh0, nh0) ----------------
    VMCNT10;
    SBAR;
    stage(A + (size_t)(mBase + 128) * lda + k1, lda, bufN + 8192);     // A1(t+1)
#pragma unroll
    for (int mi = 0; mi < 4; ++mi) {
      int row = wr * 64 + mi * 16 + lr16;                              // A half0
#pragma unroll
      for (int kk = 0; kk < 2; ++kk) {
        int p = (kk * 4 + hi) ^ (row & 7);
        af[mi][kk] = *(const bf16x8*)&bufA[row * 64 + p * 8];
      }
    }
#pragma unroll
    for (int ni = 0; ni < 2; ++ni) {
      int row = wc * 32 + ni * 16 + lr16;                              // B half0
#pragma unroll
      for (int kk = 0; kk < 2; ++kk) {
        int p = (kk * 4 + hi) ^ (row & 7);
        b0[ni][kk] = *(const bf16x8*)&bufB[row * 64 + p * 8];
      }
    }
    LGKM0;
    __builtin_amdgcn_s_setprio(1);
#pragma unroll
    for (int kk = 0; kk < 2; ++kk)
#pragma unroll
      for (int mi = 0; mi < 4; ++mi)
#pragma unroll
        for (int ni = 0; ni < 2; ++ni)
          acc[mi][ni] = __builtin_amdgcn_mfma_f32_16x16x32_bf16(af[mi][kk], b0[ni][kk], acc[mi][ni], 0, 0, 0);
    __builtin_amdgcn_s_setprio(0);

    // ---------------- phase 2: (mh0, nh1) ----------------
    VMCNT10;
    SBAR;
    stage(B + (size_t)nBase * ldb + k2, ldb, bufB);                    // B0(t+2)
#pragma unroll
    for (int ni = 0; ni < 2; ++ni) {
      int row = 128 + wc * 32 + ni * 16 + lr16;                        // B half1
#pragma unroll
      for (int kk = 0; kk < 2; ++kk) {
        int p = (kk * 4 + hi) ^ (row & 7);
        b1[ni][kk] = *(const bf16x8*)&bufB[row * 64 + p * 8];
      }
    }
    LGKM0;
    __builtin_amdgcn_s_setprio(1);
#pragma unroll
    for (int kk = 0; kk < 2; ++kk)
#pragma unroll
      for (int mi = 0; mi < 4; ++mi)
#pragma unroll
        for (int ni = 0; ni < 2; ++ni)
          acc[mi][2 + ni] = __builtin_amdgcn_mfma_f32_16x16x32_bf16(af[mi][kk], b1[ni][kk], acc[mi][2 + ni], 0, 0, 0);
    __builtin_amdgcn_s_setprio(0);

    // ---------------- phase 3: (mh1, nh1) ----------------
    VMCNT10;
    SBAR;
    stage(A + (size_t)mBase * lda + k2, lda, bufA);                    // A0(t+2)
#pragma unroll
    for (int mi = 0; mi < 4; ++mi) {
      int row = 128 + wr * 64 + mi * 16 + lr16;                        // A half1
#pragma unroll
      for (int kk = 0; kk < 2; ++kk) {
        int p = (kk * 4 + hi) ^ (row & 7);
        af[mi][kk] = *(const bf16x8*)&bufA[row * 64 + p * 8];
      }
    }
    LGKM0;
    __builtin_amdgcn_s_setprio(1);
#pragma unroll
    for (int kk = 0; kk < 2; ++kk)
#pragma unroll
      for (int mi = 0; mi < 4; ++mi)
#pragma unroll
        for (int ni = 0; ni < 2; ++ni)
          acc[4 + mi][2 + ni] = __builtin_amdgcn_mfma_f32_16x16x32_bf16(af[mi][kk], b1[ni][kk], acc[4 + mi][2 + ni], 0, 0, 0);
    __builtin_amdgcn_s_setprio(0);

    // ---------------- phase 4: (mh1, nh0) ----------------
    SBAR;
    stage(B + (size_t)(nBase + 128) * ldb + k2, ldb, bufB + 8192);     // B1(t+2)
    __builtin_amdgcn_s_setprio(1);
#pragma unroll
    for (int kk = 0; kk < 2; ++kk)
#pragma unroll
      for (int mi = 0; mi < 4; ++mi)
#pragma unroll
        for (int ni = 0; ni < 2; ++ni)
          acc[4 + mi][ni] = __builtin_amdgcn_mfma_f32_16x16x32_bf16(af[mi][kk], b0[ni][kk], acc[4 + mi][ni], 0, 0, 0);
    __builtin_amdgcn_s_setprio(0);
  }

  // epilogue
#pragma unroll
  for (int m = 0; m < 8; ++m) {
    int row0 = mBase + (m >> 2) * 128 + wr * 64 + (m & 3) * 16 + hi * 4;
#pragma unroll
    for (int n = 0; n < 4; ++n) {
      int col = nBase + (n >> 1) * 128 + wc * 32 + (n & 1) * 16 + lr16;
      f32x4 v = acc[m][n];
      if (F32OUT) {
        float* Cf = (float*)C;
#pragma unroll
        for (int r = 0; r < 4; ++r) Cf[(size_t)(row0 + r) * ldc + col] = v[r];
      } else {
        u16* Cb = (u16*)C;
#pragma unroll
        for (int r = 0; r < 4; ++r) Cb[(size_t)(row0 + r) * ldc + col] = f2bf(v[r]);
      }
    }
  }
}

// out_b = x_b @ P_b : A=xb (16384 rows), B=PT[batch], C=out f32. grid (4,64).
__global__ __launch_bounds__(512) void gemm256_out(const u16* __restrict__ xb,
                                                   const u16* __restrict__ PT,
                                                   float* __restrict__ out) {
  __shared__ u16 lds[65536];
  int bx, by, bz;
  xcd_swizzle(bx, by, bz);
  const u16* Bp = PT + (size_t)(by >> 4) * 1048576;
  gemm256_core<true>(xb, Bp, out, 1024, 1024, 1024, 1024, by * 256, bx * 256, lds);
}

// Gram split-K partials (bf16): z=b*4+kc. grid (4,4,16).
__global__ __launch_bounds__(512) void gemm256_gram(const u16* __restrict__ xT,
                                                    u16* __restrict__ Gp) {
  __shared__ u16 lds[65536];
  int bx, by, bz;
  xcd_swizzle(bx, by, bz);
  const int b = bz >> 2, kc = bz & 3;
  const u16* Ap = xT + (size_t)b * 4096 + (size_t)kc * 1024;
  gemm256_core<false>(Ap, Ap, Gp + (size_t)bz * 1048576, 16384, 16384, 1024, 1024,
                      by * 256, bx * 256, lds);
}

// ---------- reduce 4 bf16 partials -> bf16 G ----------
__global__ void reduce_gram(const u16* __restrict__ Gp, u16* __restrict__ G) {
  const size_t MW = 1048576;
  int b = blockIdx.y;
  size_t i = ((size_t)blockIdx.x * 256 + threadIdx.x) * 8;
  const u16* p = Gp + (size_t)b * 4 * MW + i;
  u16 a0[8], a1[8], a2[8], a3[8], o[8];
  *(uint4*)a0 = *(const uint4*)&p[0];
  *(uint4*)a1 = *(const uint4*)&p[MW];
  *(uint4*)a2 = *(const uint4*)&p[2 * MW];
  *(uint4*)a3 = *(const uint4*)&p[3 * MW];
#pragma unroll
  for (int j = 0; j < 8; ++j)
    o[j] = f2bf(bf2f(a0[j]) + bf2f(a1[j]) + bf2f(a2[j]) + bf2f(a3[j]));
  *(uint4*)&G[b * MW + i] = *(const uint4*)o;
}

// ---------------- host-side orchestration ----------------
// out_b = x_b @ W1 @ G_b @ W2 ; W1 = wq wk^T, W2 = wv wo, G_b = x_b^T x_b.
extern "C" void kernel_launch(void* const* d_in, const int* in_sizes, int n_in,
                              void* d_out, int out_size, void* d_ws, size_t ws_size,
                              hipStream_t stream) {
  const float* x  = (const float*)d_in[0];
  const float* wq = (const float*)d_in[1];
  const float* wk = (const float*)d_in[2];
  const float* wv = (const float*)d_in[3];
  const float* wo = (const float*)d_in[4];
  float* out = (float*)d_out;

  u16* ws = (u16*)d_ws;
  const size_t MW = 1048576;
  u16* xb  = ws;                    // [16384][1024]
  u16* xT  = ws + 16 * MW;          // [1024][16384]
  u16* WA  = ws + 32 * MW;          // [wq][woT]
  u16* WBb = ws + 34 * MW;          // [wk][wv]
  u16* W12 = ws + 36 * MW;          // [W1][W2T]
  u16* G   = ws + 38 * MW;          // [4][1024][1024]
  u16* S   = ws + 42 * MW;          // [4]
  u16* PT  = ws + 46 * MW;          // [4]
  u16* Gp  = ws + 50 * MW;          // [16][1024][1024] bf16 partials (32 MB)

  // casts (2 launches)
  cast_x_tr<<<dim3(16, 256), 256, 0, stream>>>(x, xb, xT);
  cast_weights<<<dim3(16, 16, 4), 256, 0, stream>>>(wq, wk, wv, wo, WA, WBb);

  // merged small: W1 = NT(wq, wk), W2T = NT(woT, wv)   [8-wave 128^2]
  gemm_bt8<<<dim3(8, 8, 2), 512, 0, stream>>>(WA, WBb, W12,
                                              1024, 1024, 1024, 1024,
                                              MW, MW, MW);
  // Gram split-K on the 8-phase 256^2 kernel (bf16 partials)
  gemm256_gram<<<dim3(4, 4, 16), 512, 0, stream>>>(xT, Gp);
  reduce_gram<<<dim3(512, 4), 256, 0, stream>>>(Gp, G);

  // S_b = NT(W2T, G_b)   [8-wave 128^2]
  gemm_bt8<<<dim3(8, 8, 4), 512, 0, stream>>>(W12 + MW, G, S,
                                              1024, 1024, 1024, 1024,
                                              0, MW, MW);
  // PT_b = NT(S_b, W1)   [8-wave 128^2]
  gemm_bt8<<<dim3(8, 8, 4), 512, 0, stream>>>(S, W12, PT,
                                              1024, 1024, 1024, 1024,
                                              MW, 0, MW);
  // out_b = x_b @ P_b on the 8-phase 256^2 kernel (f32 out)
  gemm256_out<<<dim3(4, 64), 512, 0, stream>>>(xb, PT, out);
}

// Round 8
// 164.543 us; speedup vs baseline: 4.3504x; 1.0380x over previous
//
#include <hip/hip_runtime.h>
#include <hip/hip_bf16.h>
#include <stdint.h>

typedef unsigned short u16;
typedef short bf16x8 __attribute__((ext_vector_type(8)));
typedef float f32x4 __attribute__((ext_vector_type(4)));

#define GLOAD16(gp, lp) __builtin_amdgcn_global_load_lds( \
    (const __attribute__((address_space(1))) uint32_t*)(gp), \
    (__attribute__((address_space(3))) uint32_t*)(lp), 16, 0, 0)

#define VMCNT10 do { asm volatile("s_waitcnt vmcnt(10)" ::: "memory"); \
                     __builtin_amdgcn_sched_barrier(0); } while (0)
#define SBAR    do { __builtin_amdgcn_s_barrier(); \
                     __builtin_amdgcn_sched_barrier(0); } while (0)
#define LGKM0   do { asm volatile("s_waitcnt lgkmcnt(0)" ::: "memory"); \
                     __builtin_amdgcn_sched_barrier(0); } while (0)

__device__ __forceinline__ u16 f2bf(float f) {
  union { float f; uint32_t u; } x; x.f = f;
  return (u16)((x.u + 0x7FFFu + ((x.u >> 16) & 1u)) >> 16);
}
__device__ __forceinline__ float bf2f(u16 h) {
  union { uint32_t u; float f; } x; x.u = (uint32_t)h << 16;
  return x.f;
}

// Bijective XCD-chunked block swizzle (T1, m204 form). Requires nwg % 8 == 0.
__device__ __forceinline__ void xcd_swizzle(int& bx, int& by, int& bz) {
  const int gx = gridDim.x, gy = gridDim.y;
  const int nwg = gx * gy * (int)gridDim.z;
  const int lin = ((int)blockIdx.z * gy + (int)blockIdx.y) * gx + (int)blockIdx.x;
  const int q = nwg >> 3;
  const int wl = (lin & 7) * q + (lin >> 3);
  bz = wl / (gx * gy);
  const int rem = wl - bz * gx * gy;
  by = rem / gx;
  bx = rem - by * gx;
}

// ------- merged cast: lin<4096 -> x (plain + transposed); else weights -------
// weights: z=0..2 plain (wq,wk,wv), z=3 transpose (wo)
__global__ __launch_bounds__(256) void cast_all(const float* __restrict__ x,
                                                const float* __restrict__ wq,
                                                const float* __restrict__ wk,
                                                const float* __restrict__ wv,
                                                const float* __restrict__ wo,
                                                u16* __restrict__ xb,
                                                u16* __restrict__ xT,
                                                u16* __restrict__ WA,
                                                u16* __restrict__ WBb) {
  __shared__ float tile[64][65];
  const int lin = blockIdx.x;
  const int t = threadIdx.x;
  const int lr = t >> 2, lc = (t & 3) * 16;
  if (lin < 4096) {
    const int d0 = (lin & 15) * 64;
    const int t0 = (lin >> 4) * 64;
    const float* src = x + (size_t)(t0 + lr) * 1024 + d0 + lc;
    u16 pl[16];
#pragma unroll
    for (int j = 0; j < 4; ++j) {
      float4 v = *(const float4*)&src[j * 4];
      tile[lr][lc + j * 4 + 0] = v.x;
      tile[lr][lc + j * 4 + 1] = v.y;
      tile[lr][lc + j * 4 + 2] = v.z;
      tile[lr][lc + j * 4 + 3] = v.w;
      pl[j * 4 + 0] = f2bf(v.x); pl[j * 4 + 1] = f2bf(v.y);
      pl[j * 4 + 2] = f2bf(v.z); pl[j * 4 + 3] = f2bf(v.w);
    }
    u16* pdst = xb + (size_t)(t0 + lr) * 1024 + d0 + lc;
    *(uint4*)&pdst[0] = *(const uint4*)&pl[0];
    *(uint4*)&pdst[8] = *(const uint4*)&pl[8];
    __syncthreads();
    u16 tr[16];
#pragma unroll
    for (int j = 0; j < 16; ++j) tr[j] = f2bf(tile[lc + j][lr]);
    u16* tdst = xT + (size_t)(d0 + lr) * 16384 + t0 + lc;
    *(uint4*)&tdst[0] = *(const uint4*)&tr[0];
    *(uint4*)&tdst[8] = *(const uint4*)&tr[8];
  } else {
    const int w = lin - 4096;
    const int z = w >> 8, tl = w & 255;
    const int r0 = (tl >> 4) * 64, c0 = (tl & 15) * 64;
    const float* in = z == 0 ? wq : z == 1 ? wk : z == 2 ? wv : wo;
    u16* o = z == 0 ? WA : z == 1 ? WBb : z == 2 ? WBb + 1048576 : WA + 1048576;
    const float* src = in + (size_t)(r0 + lr) * 1024 + c0 + lc;
    if (z < 3) {
      u16 p[16];
#pragma unroll
      for (int j = 0; j < 4; ++j) {
        float4 v = *(const float4*)&src[j * 4];
        p[j * 4 + 0] = f2bf(v.x); p[j * 4 + 1] = f2bf(v.y);
        p[j * 4 + 2] = f2bf(v.z); p[j * 4 + 3] = f2bf(v.w);
      }
      u16* dst = o + (size_t)(r0 + lr) * 1024 + c0 + lc;
      *(uint4*)&dst[0] = *(const uint4*)&p[0];
      *(uint4*)&dst[8] = *(const uint4*)&p[8];
    } else {
#pragma unroll
      for (int j = 0; j < 4; ++j) {
        float4 v = *(const float4*)&src[j * 4];
        tile[lr][lc + j * 4 + 0] = v.x;
        tile[lr][lc + j * 4 + 1] = v.y;
        tile[lr][lc + j * 4 + 2] = v.z;
        tile[lr][lc + j * 4 + 3] = v.w;
      }
      __syncthreads();
      u16 tr[16];
#pragma unroll
      for (int j = 0; j < 16; ++j) tr[j] = f2bf(tile[lc + j][lr]);
      u16* dst = o + (size_t)(c0 + lr) * 1024 + r0 + lc;
      *(uint4*)&dst[0] = *(const uint4*)&tr[0];
      *(uint4*)&dst[8] = *(const uint4*)&tr[8];
    }
  }
}

// ------- 8-wave 128^2 batched NT GEMM (small matrices) ----
__global__ __launch_bounds__(512) void gemm_bt8(const u16* __restrict__ A,
                                                const u16* __restrict__ B,
                                                u16* __restrict__ C,
                                                int lda, int ldb, int ldc, int K,
                                                size_t sA, size_t sB, size_t sC) {
  __shared__ u16 lds[2 * 8192];
  int bx, by, bz;
  xcd_swizzle(bx, by, bz);
  A += (size_t)bz * sA;
  B += (size_t)bz * sB;
  const int t = threadIdx.x;
  const int l = t & 63;
  const int wid = t >> 6;
  const int wr = wid >> 2, wc = wid & 3;
  const int lr16 = l & 15, hi = l >> 4;
  const int mBase = by * 128;
  const int nBase = bx * 128;

  f32x4 acc[4][2];
#pragma unroll
  for (int m = 0; m < 4; ++m)
#pragma unroll
    for (int n = 0; n < 2; ++n) acc[m][n] = (f32x4){0.f, 0.f, 0.f, 0.f};

  for (int kt = 0; kt < K; kt += 64) {
    __syncthreads();
#pragma unroll
    for (int i = 0; i < 2; ++i) {
      int s = i * 512 + t;
      int row = s >> 3, cp = s & 7;
      int clog = cp ^ (row & 7);
      GLOAD16(A + (size_t)(mBase + row) * lda + kt + clog * 8, &lds[s * 8]);
    }
#pragma unroll
    for (int i = 0; i < 2; ++i) {
      int s = i * 512 + t;
      int row = s >> 3, cp = s & 7;
      int clog = cp ^ (row & 7);
      GLOAD16(B + (size_t)(nBase + row) * ldb + kt + clog * 8, &lds[8192 + s * 8]);
    }
    asm volatile("s_waitcnt vmcnt(0)" ::: "memory");
    __syncthreads();
#pragma unroll
    for (int ks = 0; ks < 2; ++ks) {
      bf16x8 af[4], bfr[2];
#pragma unroll
      for (int m = 0; m < 4; ++m) {
        int row = wr * 64 + m * 16 + lr16;
        int p = (ks * 4 + hi) ^ (row & 7);
        af[m] = *(const bf16x8*)&lds[row * 64 + p * 8];
      }
#pragma unroll
      for (int n = 0; n < 2; ++n) {
        int row = wc * 32 + n * 16 + lr16;
        int p = (ks * 4 + hi) ^ (row & 7);
        bfr[n] = *(const bf16x8*)&lds[8192 + row * 64 + p * 8];
      }
#pragma unroll
      for (int m = 0; m < 4; ++m)
#pragma unroll
        for (int n = 0; n < 2; ++n)
          acc[m][n] = __builtin_amdgcn_mfma_f32_16x16x32_bf16(af[m], bfr[n], acc[m][n], 0, 0, 0);
    }
  }

#pragma unroll
  for (int m = 0; m < 4; ++m) {
    int row0 = mBase + wr * 64 + m * 16 + hi * 4;
#pragma unroll
    for (int n = 0; n < 2; ++n) {
      int col = nBase + wc * 32 + n * 16 + lr16;
      f32x4 v = acc[m][n];
      u16* Cb = C + (size_t)bz * sC;
#pragma unroll
      for (int r = 0; r < 4; ++r) Cb[(size_t)(row0 + r) * ldc + col] = f2bf(v[r]);
    }
  }
}

// ------- triangular Gram split-K: 36 lower-triangle 128^2 tiles x 16 z -------
// wl -> z (b,kc), tile t -> (ti>=tj). Partials: Gp[z][t][128][128] bf16.
__global__ __launch_bounds__(512) void gram_tri(const u16* __restrict__ xT,
                                                u16* __restrict__ Gp) {
  __shared__ u16 lds[2 * 8192];
  const int lin = blockIdx.x;
  const int wl = (lin & 7) * 72 + (lin >> 3);   // 576/8 = 72, bijective
  const int z = wl / 36, t5 = wl - z * 36;
  const int b = z >> 2, kc = z & 3;
  int ti = 0;
  while ((ti + 1) * (ti + 2) / 2 <= t5) ++ti;
  const int tj = t5 - ti * (ti + 1) / 2;
  const u16* Ap = xT + (size_t)b * 4096 + (size_t)kc * 1024;
  const int lda = 16384;
  const int mBase = ti * 128, nBase = tj * 128;

  const int t = threadIdx.x;
  const int l = t & 63;
  const int wid = t >> 6;
  const int wr = wid >> 2, wc = wid & 3;
  const int lr16 = l & 15, hi = l >> 4;

  f32x4 acc[4][2];
#pragma unroll
  for (int m = 0; m < 4; ++m)
#pragma unroll
    for (int n = 0; n < 2; ++n) acc[m][n] = (f32x4){0.f, 0.f, 0.f, 0.f};

  for (int kt = 0; kt < 1024; kt += 64) {
    __syncthreads();
#pragma unroll
    for (int i = 0; i < 2; ++i) {
      int s = i * 512 + t;
      int row = s >> 3, cp = s & 7;
      int clog = cp ^ (row & 7);
      GLOAD16(Ap + (size_t)(mBase + row) * lda + kt + clog * 8, &lds[s * 8]);
    }
#pragma unroll
    for (int i = 0; i < 2; ++i) {
      int s = i * 512 + t;
      int row = s >> 3, cp = s & 7;
      int clog = cp ^ (row & 7);
      GLOAD16(Ap + (size_t)(nBase + row) * lda + kt + clog * 8, &lds[8192 + s * 8]);
    }
    asm volatile("s_waitcnt vmcnt(0)" ::: "memory");
    __syncthreads();
#pragma unroll
    for (int ks = 0; ks < 2; ++ks) {
      bf16x8 af[4], bfr[2];
#pragma unroll
      for (int m = 0; m < 4; ++m) {
        int row = wr * 64 + m * 16 + lr16;
        int p = (ks * 4 + hi) ^ (row & 7);
        af[m] = *(const bf16x8*)&lds[row * 64 + p * 8];
      }
#pragma unroll
      for (int n = 0; n < 2; ++n) {
        int row = wc * 32 + n * 16 + lr16;
        int p = (ks * 4 + hi) ^ (row & 7);
        bfr[n] = *(const bf16x8*)&lds[8192 + row * 64 + p * 8];
      }
#pragma unroll
      for (int m = 0; m < 4; ++m)
#pragma unroll
        for (int n = 0; n < 2; ++n)
          acc[m][n] = __builtin_amdgcn_mfma_f32_16x16x32_bf16(af[m], bfr[n], acc[m][n], 0, 0, 0);
    }
  }

  u16* Cb = Gp + ((size_t)z * 36 + t5) * 16384;   // local [128][128]
#pragma unroll
  for (int m = 0; m < 4; ++m) {
    int row0 = wr * 64 + m * 16 + hi * 4;
#pragma unroll
    for (int n = 0; n < 2; ++n) {
      int col = wc * 32 + n * 16 + lr16;
      f32x4 v = acc[m][n];
#pragma unroll
      for (int r = 0; r < 4; ++r) Cb[(size_t)(row0 + r) * 128 + col] = f2bf(v[r]);
    }
  }
}

// ------- reduce 4 kc-partials of tile t, write G + mirrored transpose -------
__global__ __launch_bounds__(256) void reduce_mirror(const u16* __restrict__ Gp,
                                                     u16* __restrict__ G) {
  __shared__ u16 ldsT[128][136];   // 136: 16B-aligned rows for b128 writes
  const int t5 = blockIdx.x;       // 0..35
  const int b = blockIdx.y;        // 0..3
  int ti = 0;
  while ((ti + 1) * (ti + 2) / 2 <= t5) ++ti;
  const int tj = t5 - ti * (ti + 1) / 2;
  const int tid = threadIdx.x;
  const int rr = tid >> 4, ccc = (tid & 15) * 8;
  u16* Gb = G + (size_t)b * 1048576;
  const size_t ZS = (size_t)36 * 16384;
  const u16* base = Gp + ((size_t)(b * 4) * 36 + t5) * 16384;
#pragma unroll
  for (int i = 0; i < 8; ++i) {
    int row = i * 16 + rr;
    const u16* p = base + row * 128 + ccc;
    u16 a0[8], a1[8], a2[8], a3[8], o[8];
    *(uint4*)a0 = *(const uint4*)&p[0];
    *(uint4*)a1 = *(const uint4*)&p[ZS];
    *(uint4*)a2 = *(const uint4*)&p[2 * ZS];
    *(uint4*)a3 = *(const uint4*)&p[3 * ZS];
#pragma unroll
    for (int j = 0; j < 8; ++j)
      o[j] = f2bf(bf2f(a0[j]) + bf2f(a1[j]) + bf2f(a2[j]) + bf2f(a3[j]));
    *(uint4*)&Gb[(size_t)(ti * 128 + row) * 1024 + tj * 128 + ccc] = *(const uint4*)o;
    *(uint4*)&ldsT[row][ccc] = *(const uint4*)o;
  }
  if (ti != tj) {
    __syncthreads();
#pragma unroll
    for (int i = 0; i < 8; ++i) {
      int row = i * 16 + rr;   // row of mirrored (transposed) tile
      u16 m8[8];
#pragma unroll
      for (int j = 0; j < 8; ++j) m8[j] = ldsT[ccc + j][row];
      *(uint4*)&Gb[(size_t)(tj * 128 + row) * 1024 + ti * 128 + ccc] = *(const uint4*)m8;
    }
  }
}

// =================== 256^2 8-phase NT GEMM core ===================
template <bool F32OUT>
__device__ __forceinline__ void gemm256_core(const u16* __restrict__ A,
                                             const u16* __restrict__ B,
                                             void* __restrict__ C,
                                             int lda, int ldb, int ldc, int K,
                                             int mBase, int nBase, u16* lds) {
  const int t = threadIdx.x;
  const int l = t & 63;
  const int wid = t >> 6;
  const int wr = wid >> 2;          // 0..1
  const int wc = wid & 3;           // 0..3
  const int lr16 = l & 15, hi = l >> 4;
  const int rl0 = t >> 3;
  const int rl1 = rl0 + 64;
  const int cp  = t & 7;
  const int cs  = cp ^ (rl0 & 7);
  const int NT = K >> 6;

  f32x4 acc[8][4];
#pragma unroll
  for (int m = 0; m < 8; ++m)
#pragma unroll
    for (int n = 0; n < 4; ++n) acc[m][n] = (f32x4){0.f, 0.f, 0.f, 0.f};

  auto stage = [&](const u16* g0, int ld, u16* d) {
    GLOAD16(g0 + (size_t)rl0 * ld + cs * 8, d + rl0 * 64 + cp * 8);
    GLOAD16(g0 + (size_t)rl1 * ld + cs * 8, d + rl1 * 64 + cp * 8);
  };
  stage(A + (size_t)mBase * lda,          lda, lds + 0);
  stage(B + (size_t)nBase * ldb,          ldb, lds + 16384);
  stage(B + (size_t)(nBase + 128) * ldb,  ldb, lds + 24576);
  stage(A + (size_t)(mBase + 128) * lda,  lda, lds + 8192);
  stage(B + (size_t)nBase * ldb + 64,         ldb, lds + 32768 + 16384);
  stage(A + (size_t)mBase * lda + 64,         lda, lds + 32768);
  stage(B + (size_t)(nBase + 128) * ldb + 64, ldb, lds + 32768 + 24576);

  bf16x8 af[4][2], b0[2][2], b1[2][2];

  for (int tt = 0; tt < NT; ++tt) {
    const int cur = tt & 1;
    u16* bufA = lds + cur * 32768;
    u16* bufB = bufA + 16384;
    u16* bufN = lds + ((tt + 1) & 1) * 32768;
    int t1 = tt + 1; if (t1 >= NT) t1 -= NT;
    int t2 = tt + 2; if (t2 >= NT) t2 -= NT;
    const int k1 = t1 * 64, k2 = t2 * 64;

    // phase 1: (mh0, nh0)
    VMCNT10;
    SBAR;
    stage(A + (size_t)(mBase + 128) * lda + k1, lda, bufN + 8192);
#pragma unroll
    for (int mi = 0; mi < 4; ++mi) {
      int row = wr * 64 + mi * 16 + lr16;
#pragma unroll
      for (int kk = 0; kk < 2; ++kk) {
        int p = (kk * 4 + hi) ^ (row & 7);
        af[mi][kk] = *(const bf16x8*)&bufA[row * 64 + p * 8];
      }
    }
#pragma unroll
    for (int ni = 0; ni < 2; ++ni) {
      int row = wc * 32 + ni * 16 + lr16;
#pragma unroll
      for (int kk = 0; kk < 2; ++kk) {
        int p = (kk * 4 + hi) ^ (row & 7);
        b0[ni][kk] = *(const bf16x8*)&bufB[row * 64 + p * 8];
      }
    }
    LGKM0;
    __builtin_amdgcn_s_setprio(1);
#pragma unroll
    for (int kk = 0; kk < 2; ++kk)
#pragma unroll
      for (int mi = 0; mi < 4; ++mi)
#pragma unroll
        for (int ni = 0; ni < 2; ++ni)
          acc[mi][ni] = __builtin_amdgcn_mfma_f32_16x16x32_bf16(af[mi][kk], b0[ni][kk], acc[mi][ni], 0, 0, 0);
    __builtin_amdgcn_s_setprio(0);

    // phase 2: (mh0, nh1)
    VMCNT10;
    SBAR;
    stage(B + (size_t)nBase * ldb + k2, ldb, bufB);
#pragma unroll
    for (int ni = 0; ni < 2; ++ni) {
      int row = 128 + wc * 32 + ni * 16 + lr16;
#pragma unroll
      for (int kk = 0; kk < 2; ++kk) {
        int p = (kk * 4 + hi) ^ (row & 7);
        b1[ni][kk] = *(const bf16x8*)&bufB[row * 64 + p * 8];
      }
    }
    LGKM0;
    __builtin_amdgcn_s_setprio(1);
#pragma unroll
    for (int kk = 0; kk < 2; ++kk)
#pragma unroll
      for (int mi = 0; mi < 4; ++mi)
#pragma unroll
        for (int ni = 0; ni < 2; ++ni)
          acc[mi][2 + ni] = __builtin_amdgcn_mfma_f32_16x16x32_bf16(af[mi][kk], b1[ni][kk], acc[mi][2 + ni], 0, 0, 0);
    __builtin_amdgcn_s_setprio(0);

    // phase 3: (mh1, nh1)
    VMCNT10;
    SBAR;
    stage(A + (size_t)mBase * lda + k2, lda, bufA);
#pragma unroll
    for (int mi = 0; mi < 4; ++mi) {
      int row = 128 + wr * 64 + mi * 16 + lr16;
#pragma unroll
      for (int kk = 0; kk < 2; ++kk) {
        int p = (kk * 4 + hi) ^ (row & 7);
        af[mi][kk] = *(const bf16x8*)&bufA[row * 64 + p * 8];
      }
    }
    LGKM0;
    __builtin_amdgcn_s_setprio(1);
#pragma unroll
    for (int kk = 0; kk < 2; ++kk)
#pragma unroll
      for (int mi = 0; mi < 4; ++mi)
#pragma unroll
        for (int ni = 0; ni < 2; ++ni)
          acc[4 + mi][2 + ni] = __builtin_amdgcn_mfma_f32_16x16x32_bf16(af[mi][kk], b1[ni][kk], acc[4 + mi][2 + ni], 0, 0, 0);
    __builtin_amdgcn_s_setprio(0);

    // phase 4: (mh1, nh0)
    SBAR;
    stage(B + (size_t)(nBase + 128) * ldb + k2, ldb, bufB + 8192);
    __builtin_amdgcn_s_setprio(1);
#pragma unroll
    for (int kk = 0; kk < 2; ++kk)
#pragma unroll
      for (int mi = 0; mi < 4; ++mi)
#pragma unroll
        for (int ni = 0; ni < 2; ++ni)
          acc[4 + mi][ni] = __builtin_amdgcn_mfma_f32_16x16x32_bf16(af[mi][kk], b0[ni][kk], acc[4 + mi][ni], 0, 0, 0);
    __builtin_amdgcn_s_setprio(0);
  }

#pragma unroll
  for (int m = 0; m < 8; ++m) {
    int row0 = mBase + (m >> 2) * 128 + wr * 64 + (m & 3) * 16 + hi * 4;
#pragma unroll
    for (int n = 0; n < 4; ++n) {
      int col = nBase + (n >> 1) * 128 + wc * 32 + (n & 1) * 16 + lr16;
      f32x4 v = acc[m][n];
      if (F32OUT) {
        float* Cf = (float*)C;
#pragma unroll
        for (int r = 0; r < 4; ++r) Cf[(size_t)(row0 + r) * ldc + col] = v[r];
      } else {
        u16* Cb = (u16*)C;
#pragma unroll
        for (int r = 0; r < 4; ++r) Cb[(size_t)(row0 + r) * ldc + col] = f2bf(v[r]);
      }
    }
  }
}

// out_b = x_b @ P_b : grid (4,64).
__global__ __launch_bounds__(512) void gemm256_out(const u16* __restrict__ xb,
                                                   const u16* __restrict__ PT,
                                                   float* __restrict__ out) {
  __shared__ u16 lds[65536];
  int bx, by, bz;
  xcd_swizzle(bx, by, bz);
  const u16* Bp = PT + (size_t)(by >> 4) * 1048576;
  gemm256_core<true>(xb, Bp, out, 1024, 1024, 1024, 1024, by * 256, bx * 256, lds);
}

// ---------------- host-side orchestration ----------------
// out_b = x_b @ W1 @ G_b @ W2 ; W1 = wq wk^T, W2 = wv wo, G_b = x_b^T x_b.
extern "C" void kernel_launch(void* const* d_in, const int* in_sizes, int n_in,
                              void* d_out, int out_size, void* d_ws, size_t ws_size,
                              hipStream_t stream) {
  const float* x  = (const float*)d_in[0];
  const float* wq = (const float*)d_in[1];
  const float* wk = (const float*)d_in[2];
  const float* wv = (const float*)d_in[3];
  const float* wo = (const float*)d_in[4];
  float* out = (float*)d_out;

  u16* ws = (u16*)d_ws;
  const size_t MW = 1048576;
  u16* xb  = ws;                    // [16384][1024]
  u16* xT  = ws + 16 * MW;          // [1024][16384]
  u16* WA  = ws + 32 * MW;          // [wq][woT]
  u16* WBb = ws + 34 * MW;          // [wk][wv]
  u16* W12 = ws + 36 * MW;          // [W1][W2T]
  u16* G   = ws + 38 * MW;          // [4][1024][1024]
  u16* S   = ws + 42 * MW;          // [4]
  u16* PT  = ws + 46 * MW;          // [4]
  u16* Gp  = ws + 50 * MW;          // [16][36][128][128] bf16 tri partials (18.9 MB)

  // all casts in one launch
  cast_all<<<5120, 256, 0, stream>>>(x, wq, wk, wv, wo, xb, xT, WA, WBb);

  // merged small: W1 = NT(wq, wk), W2T = NT(woT, wv)   [8-wave 128^2]
  gemm_bt8<<<dim3(8, 8, 2), 512, 0, stream>>>(WA, WBb, W12,
                                              1024, 1024, 1024, 1024,
                                              MW, MW, MW);
  // triangular Gram split-K (36 tiles x 16 z = 576 blocks)
  gram_tri<<<576, 512, 0, stream>>>(xT, Gp);
  reduce_mirror<<<dim3(36, 4), 256, 0, stream>>>(Gp, G);

  // S_b = NT(W2T, G_b)   [8-wave 128^2]
  gemm_bt8<<<dim3(8, 8, 4), 512, 0, stream>>>(W12 + MW, G, S,
                                              1024, 1024, 1024, 1024,
                                              0, MW, MW);
  // PT_b = NT(S_b, W1)   [8-wave 128^2]
  gemm_bt8<<<dim3(8, 8, 4), 512, 0, stream>>>(S, W12, PT,
                                              1024, 1024, 1024, 1024,
                                              MW, 0, MW);
  // out_b = x_b @ P_b on the 8-phase 256^2 kernel (f32 out)
  gemm256_out<<<dim3(4, 64), 512, 0, stream>>>(xb, PT, out);
}

// Round 9
// 156.217 us; speedup vs baseline: 4.5823x; 1.0533x over previous
//
#include <hip/hip_runtime.h>
#include <hip/hip_bf16.h>
#include <stdint.h>

typedef unsigned short u16;
typedef short bf16x8 __attribute__((ext_vector_type(8)));
typedef float f32x4 __attribute__((ext_vector_type(4)));

#define GLOAD16(gp, lp) __builtin_amdgcn_global_load_lds( \
    (const __attribute__((address_space(1))) uint32_t*)(gp), \
    (__attribute__((address_space(3))) uint32_t*)(lp), 16, 0, 0)

#define VMCNT10 do { asm volatile("s_waitcnt vmcnt(10)" ::: "memory"); \
                     __builtin_amdgcn_sched_barrier(0); } while (0)
#define SBAR    do { __builtin_amdgcn_s_barrier(); \
                     __builtin_amdgcn_sched_barrier(0); } while (0)
#define LGKM0   do { asm volatile("s_waitcnt lgkmcnt(0)" ::: "memory"); \
                     __builtin_amdgcn_sched_barrier(0); } while (0)

__device__ __forceinline__ u16 f2bf(float f) {
  union { float f; uint32_t u; } x; x.f = f;
  return (u16)((x.u + 0x7FFFu + ((x.u >> 16) & 1u)) >> 16);
}
__device__ __forceinline__ float bf2f(u16 h) {
  union { uint32_t u; float f; } x; x.u = (uint32_t)h << 16;
  return x.f;
}

// Bijective XCD-chunked block swizzle (T1, m204 form). Requires nwg % 8 == 0.
__device__ __forceinline__ void xcd_swizzle(int& bx, int& by, int& bz) {
  const int gx = gridDim.x, gy = gridDim.y;
  const int nwg = gx * gy * (int)gridDim.z;
  const int lin = ((int)blockIdx.z * gy + (int)blockIdx.y) * gx + (int)blockIdx.x;
  const int q = nwg >> 3;
  const int wl = (lin & 7) * q + (lin >> 3);
  bz = wl / (gx * gy);
  const int rem = wl - bz * gx * gy;
  by = rem / gx;
  bx = rem - by * gx;
}

// ------- merged cast -------
// lin < 1024: x tile 256t x 64d (t-inner order) -> xb plain + xT transposed
//             (512 B xT row segments; concurrent blocks pack same DRAM pages)
// lin >= 1024: weights, 64x64 tiles; z=0..2 plain (wq,wk,wv), z=3 transpose (wo)
__global__ __launch_bounds__(256) void cast_all(const float* __restrict__ x,
                                                const float* __restrict__ wq,
                                                const float* __restrict__ wk,
                                                const float* __restrict__ wv,
                                                const float* __restrict__ wo,
                                                u16* __restrict__ xb,
                                                u16* __restrict__ xT,
                                                u16* __restrict__ WA,
                                                u16* __restrict__ WBb) {
  __shared__ u16 ldsT[64][264];   // 33 KB; also reused as f32 [64][65] for wo
  const int lin = blockIdx.x;
  const int t = threadIdx.x;
  if (lin < 1024) {
    const int dt = lin >> 6;        // d tile (16), outer
    const int tt = lin & 63;        // t tile (64), inner -> adjacent blocks adjacent in t
    const int d0 = dt * 64, t0 = tt * 256;
    const int lr = t >> 2, lc = (t & 3) * 16;
#pragma unroll
    for (int i = 0; i < 4; ++i) {
      const int row = t0 + i * 64 + lr;
      const float* src = x + (size_t)row * 1024 + d0 + lc;
      u16 pl[16];
#pragma unroll
      for (int j = 0; j < 4; ++j) {
        float4 v = *(const float4*)&src[j * 4];
        pl[j * 4 + 0] = f2bf(v.x); pl[j * 4 + 1] = f2bf(v.y);
        pl[j * 4 + 2] = f2bf(v.z); pl[j * 4 + 3] = f2bf(v.w);
      }
      u16* pdst = xb + (size_t)row * 1024 + d0 + lc;
      *(uint4*)&pdst[0] = *(const uint4*)&pl[0];
      *(uint4*)&pdst[8] = *(const uint4*)&pl[8];
#pragma unroll
      for (int j = 0; j < 16; ++j) ldsT[lc + j][i * 64 + lr] = pl[j];
    }
    __syncthreads();
    // write xT: thread -> (dl = t>>2, seg = t&3), 64 u16 = 128 B each;
    // 4 threads/row -> 512 B contiguous per row.
    const int dl = t >> 2, seg = (t & 3) * 64;
    u16* dst = xT + (size_t)(d0 + dl) * 16384 + t0 + seg;
    const u16* srcl = &ldsT[dl][seg];
#pragma unroll
    for (int k = 0; k < 8; ++k)
      *(uint4*)&dst[k * 8] = *(const uint4*)&srcl[k * 8];
  } else {
    const int w = lin - 1024;
    const int z = w >> 8, tl = w & 255;
    const int r0 = (tl >> 4) * 64, c0 = (tl & 15) * 64;
    const float* in = z == 0 ? wq : z == 1 ? wk : z == 2 ? wv : wo;
    u16* o = z == 0 ? WA : z == 1 ? WBb : z == 2 ? WBb + 1048576 : WA + 1048576;
    const int lr = t >> 2, lc = (t & 3) * 16;
    const float* src = in + (size_t)(r0 + lr) * 1024 + c0 + lc;
    if (z < 3) {
      u16 p[16];
#pragma unroll
      for (int j = 0; j < 4; ++j) {
        float4 v = *(const float4*)&src[j * 4];
        p[j * 4 + 0] = f2bf(v.x); p[j * 4 + 1] = f2bf(v.y);
        p[j * 4 + 2] = f2bf(v.z); p[j * 4 + 3] = f2bf(v.w);
      }
      u16* dst = o + (size_t)(r0 + lr) * 1024 + c0 + lc;
      *(uint4*)&dst[0] = *(const uint4*)&p[0];
      *(uint4*)&dst[8] = *(const uint4*)&p[8];
    } else {
      float (*tile)[65] = (float(*)[65])ldsT;
#pragma unroll
      for (int j = 0; j < 4; ++j) {
        float4 v = *(const float4*)&src[j * 4];
        tile[lr][lc + j * 4 + 0] = v.x;
        tile[lr][lc + j * 4 + 1] = v.y;
        tile[lr][lc + j * 4 + 2] = v.z;
        tile[lr][lc + j * 4 + 3] = v.w;
      }
      __syncthreads();
      u16 tr[16];
#pragma unroll
      for (int j = 0; j < 16; ++j) tr[j] = f2bf(tile[lc + j][lr]);
      u16* dst = o + (size_t)(c0 + lr) * 1024 + r0 + lc;
      *(uint4*)&dst[0] = *(const uint4*)&tr[0];
      *(uint4*)&dst[8] = *(const uint4*)&tr[8];
    }
  }
}

// ------- fused: triangular Gram split-K (576 blocks) + W12 GEMM (128 blocks) ----
// 8-wave 128^2 NT inner loop, K=1024. wl<576: gram tile; else W12 tile.
__global__ __launch_bounds__(512) void gram_w12(const u16* __restrict__ xT,
                                                u16* __restrict__ Gp,
                                                const u16* __restrict__ WA,
                                                const u16* __restrict__ WBb,
                                                u16* __restrict__ W12) {
  __shared__ u16 lds[2 * 8192];
  const int lin = blockIdx.x;
  const int wl = (lin & 7) * 88 + (lin >> 3);   // 704/8 = 88, bijective
  const u16 *A, *B;
  u16* Cb;
  int lda, ldc;
  if (wl < 576) {
    const int z = wl / 36, t5 = wl - z * 36;
    const int b = z >> 2, kc = z & 3;
    int ti = 0;
    while ((ti + 1) * (ti + 2) / 2 <= t5) ++ti;
    const int tj = t5 - ti * (ti + 1) / 2;
    const u16* Ap = xT + (size_t)b * 4096 + (size_t)kc * 1024;
    A = Ap + (size_t)(ti * 128) * 16384;
    B = Ap + (size_t)(tj * 128) * 16384;
    lda = 16384;
    Cb = Gp + ((size_t)z * 36 + t5) * 16384;
    ldc = 128;
  } else {
    const int w = wl - 576;          // 0..127
    const int z2 = w >> 6, tl = w & 63;
    const int by = tl >> 3, bx = tl & 7;
    A = WA + (size_t)z2 * 1048576 + (size_t)(by * 128) * 1024;
    B = WBb + (size_t)z2 * 1048576 + (size_t)(bx * 128) * 1024;
    lda = 1024;
    Cb = W12 + (size_t)z2 * 1048576 + (size_t)(by * 128) * 1024 + bx * 128;
    ldc = 1024;
  }

  const int t = threadIdx.x;
  const int l = t & 63;
  const int wid = t >> 6;
  const int wr = wid >> 2, wc = wid & 3;
  const int lr16 = l & 15, hi = l >> 4;

  f32x4 acc[4][2];
#pragma unroll
  for (int m = 0; m < 4; ++m)
#pragma unroll
    for (int n = 0; n < 2; ++n) acc[m][n] = (f32x4){0.f, 0.f, 0.f, 0.f};

  for (int kt = 0; kt < 1024; kt += 64) {
    __syncthreads();
#pragma unroll
    for (int i = 0; i < 2; ++i) {
      int s = i * 512 + t;
      int row = s >> 3, cp = s & 7;
      int clog = cp ^ (row & 7);
      GLOAD16(A + (size_t)row * lda + kt + clog * 8, &lds[s * 8]);
    }
#pragma unroll
    for (int i = 0; i < 2; ++i) {
      int s = i * 512 + t;
      int row = s >> 3, cp = s & 7;
      int clog = cp ^ (row & 7);
      GLOAD16(B + (size_t)row * lda + kt + clog * 8, &lds[8192 + s * 8]);
    }
    asm volatile("s_waitcnt vmcnt(0)" ::: "memory");
    __syncthreads();
#pragma unroll
    for (int ks = 0; ks < 2; ++ks) {
      bf16x8 af[4], bfr[2];
#pragma unroll
      for (int m = 0; m < 4; ++m) {
        int row = wr * 64 + m * 16 + lr16;
        int p = (ks * 4 + hi) ^ (row & 7);
        af[m] = *(const bf16x8*)&lds[row * 64 + p * 8];
      }
#pragma unroll
      for (int n = 0; n < 2; ++n) {
        int row = wc * 32 + n * 16 + lr16;
        int p = (ks * 4 + hi) ^ (row & 7);
        bfr[n] = *(const bf16x8*)&lds[8192 + row * 64 + p * 8];
      }
#pragma unroll
      for (int m = 0; m < 4; ++m)
#pragma unroll
        for (int n = 0; n < 2; ++n)
          acc[m][n] = __builtin_amdgcn_mfma_f32_16x16x32_bf16(af[m], bfr[n], acc[m][n], 0, 0, 0);
    }
  }

#pragma unroll
  for (int m = 0; m < 4; ++m) {
    int row0 = wr * 64 + m * 16 + hi * 4;
#pragma unroll
    for (int n = 0; n < 2; ++n) {
      int col = wc * 32 + n * 16 + lr16;
      f32x4 v = acc[m][n];
#pragma unroll
      for (int r = 0; r < 4; ++r) Cb[(size_t)(row0 + r) * ldc + col] = f2bf(v[r]);
    }
  }
}

// ------- 8-wave 128^2 batched NT GEMM (small matrices) ----
__global__ __launch_bounds__(512) void gemm_bt8(const u16* __restrict__ A,
                                                const u16* __restrict__ B,
                                                u16* __restrict__ C,
                                                int lda, int ldb, int ldc, int K,
                                                size_t sA, size_t sB, size_t sC) {
  __shared__ u16 lds[2 * 8192];
  int bx, by, bz;
  xcd_swizzle(bx, by, bz);
  A += (size_t)bz * sA;
  B += (size_t)bz * sB;
  const int t = threadIdx.x;
  const int l = t & 63;
  const int wid = t >> 6;
  const int wr = wid >> 2, wc = wid & 3;
  const int lr16 = l & 15, hi = l >> 4;
  const int mBase = by * 128;
  const int nBase = bx * 128;

  f32x4 acc[4][2];
#pragma unroll
  for (int m = 0; m < 4; ++m)
#pragma unroll
    for (int n = 0; n < 2; ++n) acc[m][n] = (f32x4){0.f, 0.f, 0.f, 0.f};

  for (int kt = 0; kt < K; kt += 64) {
    __syncthreads();
#pragma unroll
    for (int i = 0; i < 2; ++i) {
      int s = i * 512 + t;
      int row = s >> 3, cp = s & 7;
      int clog = cp ^ (row & 7);
      GLOAD16(A + (size_t)(mBase + row) * lda + kt + clog * 8, &lds[s * 8]);
    }
#pragma unroll
    for (int i = 0; i < 2; ++i) {
      int s = i * 512 + t;
      int row = s >> 3, cp = s & 7;
      int clog = cp ^ (row & 7);
      GLOAD16(B + (size_t)(nBase + row) * ldb + kt + clog * 8, &lds[8192 + s * 8]);
    }
    asm volatile("s_waitcnt vmcnt(0)" ::: "memory");
    __syncthreads();
#pragma unroll
    for (int ks = 0; ks < 2; ++ks) {
      bf16x8 af[4], bfr[2];
#pragma unroll
      for (int m = 0; m < 4; ++m) {
        int row = wr * 64 + m * 16 + lr16;
        int p = (ks * 4 + hi) ^ (row & 7);
        af[m] = *(const bf16x8*)&lds[row * 64 + p * 8];
      }
#pragma unroll
      for (int n = 0; n < 2; ++n) {
        int row = wc * 32 + n * 16 + lr16;
        int p = (ks * 4 + hi) ^ (row & 7);
        bfr[n] = *(const bf16x8*)&lds[8192 + row * 64 + p * 8];
      }
#pragma unroll
      for (int m = 0; m < 4; ++m)
#pragma unroll
        for (int n = 0; n < 2; ++n)
          acc[m][n] = __builtin_amdgcn_mfma_f32_16x16x32_bf16(af[m], bfr[n], acc[m][n], 0, 0, 0);
    }
  }

#pragma unroll
  for (int m = 0; m < 4; ++m) {
    int row0 = mBase + wr * 64 + m * 16 + hi * 4;
#pragma unroll
    for (int n = 0; n < 2; ++n) {
      int col = nBase + wc * 32 + n * 16 + lr16;
      f32x4 v = acc[m][n];
      u16* Cb = C + (size_t)bz * sC;
#pragma unroll
      for (int r = 0; r < 4; ++r) Cb[(size_t)(row0 + r) * ldc + col] = f2bf(v[r]);
    }
  }
}

// ------- reduce 4 kc-partials of tile t, write G + mirrored transpose -------
__global__ __launch_bounds__(256) void reduce_mirror(const u16* __restrict__ Gp,
                                                     u16* __restrict__ G) {
  __shared__ u16 ldsT[128][136];
  const int t5 = blockIdx.x;       // 0..35
  const int b = blockIdx.y;        // 0..3
  int ti = 0;
  while ((ti + 1) * (ti + 2) / 2 <= t5) ++ti;
  const int tj = t5 - ti * (ti + 1) / 2;
  const int tid = threadIdx.x;
  const int rr = tid >> 4, ccc = (tid & 15) * 8;
  u16* Gb = G + (size_t)b * 1048576;
  const size_t ZS = (size_t)36 * 16384;
  const u16* base = Gp + ((size_t)(b * 4) * 36 + t5) * 16384;
#pragma unroll
  for (int i = 0; i < 8; ++i) {
    int row = i * 16 + rr;
    const u16* p = base + row * 128 + ccc;
    u16 a0[8], a1[8], a2[8], a3[8], o[8];
    *(uint4*)a0 = *(const uint4*)&p[0];
    *(uint4*)a1 = *(const uint4*)&p[ZS];
    *(uint4*)a2 = *(const uint4*)&p[2 * ZS];
    *(uint4*)a3 = *(const uint4*)&p[3 * ZS];
#pragma unroll
    for (int j = 0; j < 8; ++j)
      o[j] = f2bf(bf2f(a0[j]) + bf2f(a1[j]) + bf2f(a2[j]) + bf2f(a3[j]));
    *(uint4*)&Gb[(size_t)(ti * 128 + row) * 1024 + tj * 128 + ccc] = *(const uint4*)o;
    *(uint4*)&ldsT[row][ccc] = *(const uint4*)o;
  }
  if (ti != tj) {
    __syncthreads();
#pragma unroll
    for (int i = 0; i < 8; ++i) {
      int row = i * 16 + rr;
      u16 m8[8];
#pragma unroll
      for (int j = 0; j < 8; ++j) m8[j] = ldsT[ccc + j][row];
      *(uint4*)&Gb[(size_t)(tj * 128 + row) * 1024 + ti * 128 + ccc] = *(const uint4*)m8;
    }
  }
}

// =================== 256^2 8-phase NT GEMM core ===================
template <bool F32OUT>
__device__ __forceinline__ void gemm256_core(const u16* __restrict__ A,
                                             const u16* __restrict__ B,
                                             void* __restrict__ C,
                                             int lda, int ldb, int ldc, int K,
                                             int mBase, int nBase, u16* lds) {
  const int t = threadIdx.x;
  const int l = t & 63;
  const int wid = t >> 6;
  const int wr = wid >> 2;
  const int wc = wid & 3;
  const int lr16 = l & 15, hi = l >> 4;
  const int rl0 = t >> 3;
  const int rl1 = rl0 + 64;
  const int cp  = t & 7;
  const int cs  = cp ^ (rl0 & 7);
  const int NT = K >> 6;

  f32x4 acc[8][4];
#pragma unroll
  for (int m = 0; m < 8; ++m)
#pragma unroll
    for (int n = 0; n < 4; ++n) acc[m][n] = (f32x4){0.f, 0.f, 0.f, 0.f};

  auto stage = [&](const u16* g0, int ld, u16* d) {
    GLOAD16(g0 + (size_t)rl0 * ld + cs * 8, d + rl0 * 64 + cp * 8);
    GLOAD16(g0 + (size_t)rl1 * ld + cs * 8, d + rl1 * 64 + cp * 8);
  };
  stage(A + (size_t)mBase * lda,          lda, lds + 0);
  stage(B + (size_t)nBase * ldb,          ldb, lds + 16384);
  stage(B + (size_t)(nBase + 128) * ldb,  ldb, lds + 24576);
  stage(A + (size_t)(mBase + 128) * lda,  lda, lds + 8192);
  stage(B + (size_t)nBase * ldb + 64,         ldb, lds + 32768 + 16384);
  stage(A + (size_t)mBase * lda + 64,         lda, lds + 32768);
  stage(B + (size_t)(nBase + 128) * ldb + 64, ldb, lds + 32768 + 24576);

  bf16x8 af[4][2], b0[2][2], b1[2][2];

  for (int tt = 0; tt < NT; ++tt) {
    const int cur = tt & 1;
    u16* bufA = lds + cur * 32768;
    u16* bufB = bufA + 16384;
    u16* bufN = lds + ((tt + 1) & 1) * 32768;
    int t1 = tt + 1; if (t1 >= NT) t1 -= NT;
    int t2 = tt + 2; if (t2 >= NT) t2 -= NT;
    const int k1 = t1 * 64, k2 = t2 * 64;

    // phase 1: (mh0, nh0)
    VMCNT10;
    SBAR;
    stage(A + (size_t)(mBase + 128) * lda + k1, lda, bufN + 8192);
#pragma unroll
    for (int mi = 0; mi < 4; ++mi) {
      int row = wr * 64 + mi * 16 + lr16;
#pragma unroll
      for (int kk = 0; kk < 2; ++kk) {
        int p = (kk * 4 + hi) ^ (row & 7);
        af[mi][kk] = *(const bf16x8*)&bufA[row * 64 + p * 8];
      }
    }
#pragma unroll
    for (int ni = 0; ni < 2; ++ni) {
      int row = wc * 32 + ni * 16 + lr16;
#pragma unroll
      for (int kk = 0; kk < 2; ++kk) {
        int p = (kk * 4 + hi) ^ (row & 7);
        b0[ni][kk] = *(const bf16x8*)&bufB[row * 64 + p * 8];
      }
    }
    LGKM0;
    __builtin_amdgcn_s_setprio(1);
#pragma unroll
    for (int kk = 0; kk < 2; ++kk)
#pragma unroll
      for (int mi = 0; mi < 4; ++mi)
#pragma unroll
        for (int ni = 0; ni < 2; ++ni)
          acc[mi][ni] = __builtin_amdgcn_mfma_f32_16x16x32_bf16(af[mi][kk], b0[ni][kk], acc[mi][ni], 0, 0, 0);
    __builtin_amdgcn_s_setprio(0);

    // phase 2: (mh0, nh1)
    VMCNT10;
    SBAR;
    stage(B + (size_t)nBase * ldb + k2, ldb, bufB);
#pragma unroll
    for (int ni = 0; ni < 2; ++ni) {
      int row = 128 + wc * 32 + ni * 16 + lr16;
#pragma unroll
      for (int kk = 0; kk < 2; ++kk) {
        int p = (kk * 4 + hi) ^ (row & 7);
        b1[ni][kk] = *(const bf16x8*)&bufB[row * 64 + p * 8];
      }
    }
    LGKM0;
    __builtin_amdgcn_s_setprio(1);
#pragma unroll
    for (int kk = 0; kk < 2; ++kk)
#pragma unroll
      for (int mi = 0; mi < 4; ++mi)
#pragma unroll
        for (int ni = 0; ni < 2; ++ni)
          acc[mi][2 + ni] = __builtin_amdgcn_mfma_f32_16x16x32_bf16(af[mi][kk], b1[ni][kk], acc[mi][2 + ni], 0, 0, 0);
    __builtin_amdgcn_s_setprio(0);

    // phase 3: (mh1, nh1)
    VMCNT10;
    SBAR;
    stage(A + (size_t)mBase * lda + k2, lda, bufA);
#pragma unroll
    for (int mi = 0; mi < 4; ++mi) {
      int row = 128 + wr * 64 + mi * 16 + lr16;
#pragma unroll
      for (int kk = 0; kk < 2; ++kk) {
        int p = (kk * 4 + hi) ^ (row & 7);
        af[mi][kk] = *(const bf16x8*)&bufA[row * 64 + p * 8];
      }
    }
    LGKM0;
    __builtin_amdgcn_s_setprio(1);
#pragma unroll
    for (int kk = 0; kk < 2; ++kk)
#pragma unroll
      for (int mi = 0; mi < 4; ++mi)
#pragma unroll
        for (int ni = 0; ni < 2; ++ni)
          acc[4 + mi][2 + ni] = __builtin_amdgcn_mfma_f32_16x16x32_bf16(af[mi][kk], b1[ni][kk], acc[4 + mi][2 + ni], 0, 0, 0);
    __builtin_amdgcn_s_setprio(0);

    // phase 4: (mh1, nh0)
    SBAR;
    stage(B + (size_t)(nBase + 128) * ldb + k2, ldb, bufB + 8192);
    __builtin_amdgcn_s_setprio(1);
#pragma unroll
    for (int kk = 0; kk < 2; ++kk)
#pragma unroll
      for (int mi = 0; mi < 4; ++mi)
#pragma unroll
        for (int ni = 0; ni < 2; ++ni)
          acc[4 + mi][ni] = __builtin_amdgcn_mfma_f32_16x16x32_bf16(af[mi][kk], b0[ni][kk], acc[4 + mi][ni], 0, 0, 0);
    __builtin_amdgcn_s_setprio(0);
  }

#pragma unroll
  for (int m = 0; m < 8; ++m) {
    int row0 = mBase + (m >> 2) * 128 + wr * 64 + (m & 3) * 16 + hi * 4;
#pragma unroll
    for (int n = 0; n < 4; ++n) {
      int col = nBase + (n >> 1) * 128 + wc * 32 + (n & 1) * 16 + lr16;
      f32x4 v = acc[m][n];
      if (F32OUT) {
        float* Cf = (float*)C;
#pragma unroll
        for (int r = 0; r < 4; ++r) Cf[(size_t)(row0 + r) * ldc + col] = v[r];
      } else {
        u16* Cb = (u16*)C;
#pragma unroll
        for (int r = 0; r < 4; ++r) Cb[(size_t)(row0 + r) * ldc + col] = f2bf(v[r]);
      }
    }
  }
}

// out_b = x_b @ P_b : grid (4,64).
__global__ __launch_bounds__(512) void gemm256_out(const u16* __restrict__ xb,
                                                   const u16* __restrict__ PT,
                                                   float* __restrict__ out) {
  __shared__ u16 lds[65536];
  int bx, by, bz;
  xcd_swizzle(bx, by, bz);
  const u16* Bp = PT + (size_t)(by >> 4) * 1048576;
  gemm256_core<true>(xb, Bp, out, 1024, 1024, 1024, 1024, by * 256, bx * 256, lds);
}

// ---------------- host-side orchestration ----------------
// out_b = x_b @ W1 @ G_b @ W2 ; W1 = wq wk^T, W2 = wv wo, G_b = x_b^T x_b.
extern "C" void kernel_launch(void* const* d_in, const int* in_sizes, int n_in,
                              void* d_out, int out_size, void* d_ws, size_t ws_size,
                              hipStream_t stream) {
  const float* x  = (const float*)d_in[0];
  const float* wq = (const float*)d_in[1];
  const float* wk = (const float*)d_in[2];
  const float* wv = (const float*)d_in[3];
  const float* wo = (const float*)d_in[4];
  float* out = (float*)d_out;

  u16* ws = (u16*)d_ws;
  const size_t MW = 1048576;
  u16* xb  = ws;                    // [16384][1024]
  u16* xT  = ws + 16 * MW;          // [1024][16384]
  u16* WA  = ws + 32 * MW;          // [wq][woT]
  u16* WBb = ws + 34 * MW;          // [wk][wv]
  u16* W12 = ws + 36 * MW;          // [W1][W2T]
  u16* G   = ws + 38 * MW;          // [4][1024][1024]
  u16* S   = ws + 42 * MW;          // [4]
  u16* PT  = ws + 46 * MW;          // [4]
  u16* Gp  = ws + 50 * MW;          // [16][36][128][128] bf16 tri partials

  // all casts in one launch (1024 x-tiles + 1024 weight-tiles)
  cast_all<<<2048, 256, 0, stream>>>(x, wq, wk, wv, wo, xb, xT, WA, WBb);

  // fused: triangular Gram split-K (576) + W12 GEMM (128)
  gram_w12<<<704, 512, 0, stream>>>(xT, Gp, WA, WBb, W12);
  reduce_mirror<<<dim3(36, 4), 256, 0, stream>>>(Gp, G);

  // S_b = NT(W2T, G_b)   [8-wave 128^2]
  gemm_bt8<<<dim3(8, 8, 4), 512, 0, stream>>>(W12 + MW, G, S,
                                              1024, 1024, 1024, 1024,
                                              0, MW, MW);
  // PT_b = NT(S_b, W1)   [8-wave 128^2]
  gemm_bt8<<<dim3(8, 8, 4), 512, 0, stream>>>(S, W12, PT,
                                              1024, 1024, 1024, 1024,
                                              MW, 0, MW);
  // out_b = x_b @ P_b on the 8-phase 256^2 kernel (f32 out)
  gemm256_out<<<dim3(4, 64), 512, 0, stream>>>(xb, PT, out);
}